// Round 1
// baseline (483.612 us; speedup 1.0000x reference)
//
#include <hip/hip_runtime.h>

#define B_ 4
#define T_ 2048
#define C_ 1024
#define H_ 16
#define D_ 64
#define M_ (B_*T_)    // 8192
#define N3_ (3*C_)    // 3072

typedef unsigned short u16;
typedef short bf16x8 __attribute__((ext_vector_type(8)));
typedef unsigned short u16x8 __attribute__((ext_vector_type(8)));
typedef float f32x4 __attribute__((ext_vector_type(4)));

__device__ __forceinline__ u16 f2bf(float f) {
  unsigned u = __float_as_uint(f);
  u += 0x7fffu + ((u >> 16) & 1u);
  return (u16)(u >> 16);
}
__device__ __forceinline__ float bf2f(u16 u) { return __uint_as_float(((unsigned)u) << 16); }

__device__ __forceinline__ void gload16(const void* g, void* l) {
  __builtin_amdgcn_global_load_lds((const __attribute__((address_space(1))) void*)g,
                                   (__attribute__((address_space(3))) void*)l, 16, 0, 0);
}

// ---------------- elementwise f32 -> bf16 (vectorized, G13) ----------------
__global__ __launch_bounds__(256) void k_convert(const float* __restrict__ in,
                                                 u16* __restrict__ out, int n8) {
  int i = blockIdx.x * 256 + threadIdx.x;
  if (i >= n8) return;
  f32x4 a = *(const f32x4*)(in + (size_t)i * 8);
  f32x4 b = *(const f32x4*)(in + (size_t)i * 8 + 4);
  u16x8 o;
  #pragma unroll
  for (int j = 0; j < 4; ++j) { o[j] = f2bf(a[j]); o[4 + j] = f2bf(b[j]); }
  *(u16x8*)(out + (size_t)i * 8) = o;
}

// ---------------- transpose+convert: W [K][N] f32 -> Wt [N][K] bf16 ----------------
__global__ __launch_bounds__(256) void k_transpose(const float* __restrict__ W,
                                                   u16* __restrict__ Wt, int K, int N) {
  __shared__ float tile[64][65];
  int n0 = blockIdx.x * 64, k0 = blockIdx.y * 64;
  int c = threadIdx.x & 63, r0 = threadIdx.x >> 6;
  #pragma unroll
  for (int i = 0; i < 16; ++i) {
    int r = i * 4 + r0;
    tile[r][c] = W[(size_t)(k0 + r) * N + n0 + c];
  }
  __syncthreads();
  #pragma unroll
  for (int i = 0; i < 16; ++i) {
    int r = i * 4 + r0;
    Wt[(size_t)(n0 + r) * K + k0 + c] = f2bf(tile[c][r]);
  }
}

// ---------------- RoPE cos/sin tables (double precision on device) ----------------
__global__ void k_rope_table(float* __restrict__ ct, float* __restrict__ st) {
  int idx = blockIdx.x * 256 + threadIdx.x;   // T_*32 entries
  int t = idx >> 5, i = idx & 31;
  double inv = exp(-(2.0 * (double)i / 64.0) * log(10000.0));
  double a = (double)t * inv;
  ct[idx] = (float)cos(a);
  st[idx] = (float)sin(a);
}

// ---------------- RoPE in-place on [B,H,T,D] bf16 ----------------
__global__ __launch_bounds__(256) void k_rope(u16* __restrict__ X,
                                              const float* __restrict__ ct,
                                              const float* __restrict__ st) {
  int e = blockIdx.x * 256 + threadIdx.x;     // B*H*T*8 threads, 8 elems each
  int d0 = (e & 7) * 8;
  int t = (e >> 3) & (T_ - 1);
  size_t base = (size_t)e * 8;
  u16x8 v = *(const u16x8*)(X + base);
  f32x4 cv = *(const f32x4*)(ct + t * 32 + d0 / 2);
  f32x4 sv = *(const f32x4*)(st + t * 32 + d0 / 2);
  u16x8 o;
  #pragma unroll
  for (int p = 0; p < 4; ++p) {
    float x1 = bf2f(v[2 * p]), x2 = bf2f(v[2 * p + 1]);
    o[2 * p]     = f2bf(x1 * cv[p] - x2 * sv[p]);
    o[2 * p + 1] = f2bf(x2 * cv[p] + x1 * sv[p]);
  }
  *(u16x8*)(X + base) = o;
}

// ---------------- bf16 GEMM: A[M][K] @ Bt[N][K]^T + bias ----------------
// 128x128 tile, BK=64, 4 waves (each 64x64), global_load_lds w/ pre-swizzled
// source so ds_read_b128 is bank-conflict-free (T2, slot^row&7).
// MODE 0: scatter to Q/K/V [B,H,T,D] bf16.  MODE 1: write fp32 C[M][N].
template <int MODE>
__global__ __launch_bounds__(256) void k_gemm(const u16* __restrict__ A,
                                              const u16* __restrict__ Bt,
                                              const float* __restrict__ bias,
                                              float* __restrict__ Cout,
                                              u16* __restrict__ Qb, u16* __restrict__ Kb,
                                              u16* __restrict__ Vb,
                                              int Md, int Nd, int Kd) {
  __shared__ u16 sA[128 * 64];
  __shared__ u16 sB[128 * 64];
  const int tid = threadIdx.x, lane = tid & 63, w = tid >> 6;
  const int g = lane >> 4, r = lane & 15;
  const int wm = w >> 1, wn = w & 1;
  const int tM = blockIdx.y * 128, tN = blockIdx.x * 128;

  f32x4 acc[4][4];
  #pragma unroll
  for (int i = 0; i < 4; ++i)
    #pragma unroll
    for (int j = 0; j < 4; ++j) acc[i][j] = (f32x4){0.f, 0.f, 0.f, 0.f};

  for (int k0 = 0; k0 < Kd; k0 += 64) {
    #pragma unroll
    for (int i = 0; i < 4; ++i) {
      int c = i * 256 + tid, row = c >> 3, slot = (c & 7) ^ (row & 7);
      gload16(A + (size_t)(tM + row) * Kd + k0 + slot * 8, sA + (i * 256 + w * 64) * 8);
    }
    #pragma unroll
    for (int i = 0; i < 4; ++i) {
      int c = i * 256 + tid, row = c >> 3, slot = (c & 7) ^ (row & 7);
      gload16(Bt + (size_t)(tN + row) * Kd + k0 + slot * 8, sB + (i * 256 + w * 64) * 8);
    }
    __syncthreads();
    bf16x8 af[4][2], bfr[4][2];
    #pragma unroll
    for (int mt = 0; mt < 4; ++mt)
      #pragma unroll
      for (int kk = 0; kk < 2; ++kk) {
        int row = wm * 64 + mt * 16 + r;
        af[mt][kk] = *(const bf16x8*)(sA + ((row * 64 + kk * 32 + g * 8) ^ ((row & 7) << 3)));
      }
    #pragma unroll
    for (int nt = 0; nt < 4; ++nt)
      #pragma unroll
      for (int kk = 0; kk < 2; ++kk) {
        int row = wn * 64 + nt * 16 + r;
        bfr[nt][kk] = *(const bf16x8*)(sB + ((row * 64 + kk * 32 + g * 8) ^ ((row & 7) << 3)));
      }
    #pragma unroll
    for (int mt = 0; mt < 4; ++mt)
      #pragma unroll
      for (int nt = 0; nt < 4; ++nt)
        #pragma unroll
        for (int kk = 0; kk < 2; ++kk)
          acc[mt][nt] = __builtin_amdgcn_mfma_f32_16x16x32_bf16(af[mt][kk], bfr[nt][kk],
                                                                acc[mt][nt], 0, 0, 0);
    __syncthreads();
  }

  // epilogue: C/D layout col = lane&15, row = (lane>>4)*4 + reg
  #pragma unroll
  for (int mt = 0; mt < 4; ++mt)
    #pragma unroll
    for (int nt = 0; nt < 4; ++nt) {
      int n = tN + wn * 64 + nt * 16 + r;
      float bv = bias[n];
      if (MODE == 1) {
        #pragma unroll
        for (int reg = 0; reg < 4; ++reg) {
          int m = tM + wm * 64 + mt * 16 + g * 4 + reg;
          Cout[(size_t)m * Nd + n] = acc[mt][nt][reg] + bv;
        }
      } else {
        int sec = n >> 10, idx = n & 1023, hh = idx >> 6, dd = idx & 63;
        u16* dst = sec == 0 ? Qb : (sec == 1 ? Kb : Vb);
        #pragma unroll
        for (int reg = 0; reg < 4; ++reg) {
          int m = tM + wm * 64 + mt * 16 + g * 4 + reg;
          int bb = m >> 11, tt = m & (T_ - 1);
          dst[((size_t)(bb * H_ + hh) * T_ + tt) * D_ + dd] = f2bf(acc[mt][nt][reg] + bv);
        }
      }
    }
}

// ---------------- causal flash attention, bf16 MFMA ----------------
// Block: 64 q-rows (4 waves x 16), KV tiles of 64 keys shared via LDS.
__global__ __launch_bounds__(256) void k_attn(const u16* __restrict__ Qb,
                                              const u16* __restrict__ Kb,
                                              const u16* __restrict__ Vb,
                                              u16* __restrict__ Y) {
  __shared__ u16 sK[64 * 64];   // [key][d], XOR-swizzled via pre-swizzled source
  __shared__ u16 sV[64 * 64];   // [d][key] transposed, XOR-swizzled
  __shared__ u16 sP[64 * 64];   // per-wave 16-row bands, XOR-swizzled
  const int tid = threadIdx.x, lane = tid & 63, w = tid >> 6;
  const int g = lane >> 4, r = lane & 15;
  const int qt = blockIdx.x, h = blockIdx.y, b = blockIdx.z;
  const int q0 = qt * 64;
  const size_t bh = ((size_t)b * H_ + h) * T_;

  bf16x8 qf[2];
  {
    int q = q0 + w * 16 + r;
    qf[0] = *(const bf16x8*)(Qb + (bh + q) * D_ + g * 8);
    qf[1] = *(const bf16x8*)(Qb + (bh + q) * D_ + 32 + g * 8);
  }
  float m_run[4], l_run[4];
  f32x4 o[4];
  #pragma unroll
  for (int i = 0; i < 4; ++i) {
    m_run[i] = -1e30f; l_run[i] = 0.f;
    o[i] = (f32x4){0.f, 0.f, 0.f, 0.f};
  }

  for (int kt = 0; kt <= qt; ++kt) {
    __syncthreads();
    #pragma unroll
    for (int i = 0; i < 2; ++i) {
      int c = i * 256 + tid, row = c >> 3, slot = (c & 7) ^ (row & 7);
      gload16(Kb + (bh + kt * 64 + row) * D_ + slot * 8, sK + (i * 256 + w * 64) * 8);
    }
    #pragma unroll
    for (int i = 0; i < 2; ++i) {
      int c = i * 256 + tid, key = c >> 3, d0 = (c & 7) * 8;
      u16x8 v = *(const u16x8*)(Vb + (bh + kt * 64 + key) * D_ + d0);
      #pragma unroll
      for (int j = 0; j < 8; ++j) {
        int d = d0 + j;
        sV[(d * 64 + key) ^ ((d & 7) << 3)] = v[j];
      }
    }
    __syncthreads();

    // S = Q K^T * scale
    f32x4 s[4];
    #pragma unroll
    for (int ctl = 0; ctl < 4; ++ctl) {
      f32x4 a = (f32x4){0.f, 0.f, 0.f, 0.f};
      #pragma unroll
      for (int kk = 0; kk < 2; ++kk) {
        int row = ctl * 16 + r;
        bf16x8 kf = *(const bf16x8*)(sK + ((row * 64 + kk * 32 + g * 8) ^ ((row & 7) << 3)));
        a = __builtin_amdgcn_mfma_f32_16x16x32_bf16(qf[kk], kf, a, 0, 0, 0);
      }
      s[ctl] = a * 0.125f;
    }
    if (kt == qt) {  // diagonal tile: mask key > q
      #pragma unroll
      for (int ctl = 0; ctl < 4; ++ctl)
        #pragma unroll
        for (int reg = 0; reg < 4; ++reg)
          if (ctl * 16 + r > w * 16 + g * 4 + reg) s[ctl][reg] = -1e30f;
    }
    // online softmax over 16-lane groups (rows = g*4+reg)
    float tm[4], f[4], rs[4];
    #pragma unroll
    for (int reg = 0; reg < 4; ++reg)
      tm[reg] = fmaxf(fmaxf(s[0][reg], s[1][reg]), fmaxf(s[2][reg], s[3][reg]));
    #pragma unroll
    for (int mk = 1; mk < 16; mk <<= 1)
      #pragma unroll
      for (int reg = 0; reg < 4; ++reg)
        tm[reg] = fmaxf(tm[reg], __shfl_xor(tm[reg], mk));
    #pragma unroll
    for (int reg = 0; reg < 4; ++reg) {
      float mn = fmaxf(m_run[reg], tm[reg]);
      f[reg] = __expf(m_run[reg] - mn);
      m_run[reg] = mn;
      rs[reg] = 0.f;
    }
    float ps[4][4];
    #pragma unroll
    for (int ctl = 0; ctl < 4; ++ctl)
      #pragma unroll
      for (int reg = 0; reg < 4; ++reg) {
        float p = __expf(s[ctl][reg] - m_run[reg]);
        ps[ctl][reg] = p;
        rs[reg] += p;
      }
    #pragma unroll
    for (int mk = 1; mk < 16; mk <<= 1)
      #pragma unroll
      for (int reg = 0; reg < 4; ++reg)
        rs[reg] += __shfl_xor(rs[reg], mk);
    #pragma unroll
    for (int reg = 0; reg < 4; ++reg)
      l_run[reg] = l_run[reg] * f[reg] + rs[reg];
    #pragma unroll
    for (int nt = 0; nt < 4; ++nt)
      #pragma unroll
      for (int reg = 0; reg < 4; ++reg)
        o[nt][reg] *= f[reg];
    // P -> LDS (C/D layout) then reload in A-operand layout
    #pragma unroll
    for (int ctl = 0; ctl < 4; ++ctl)
      #pragma unroll
      for (int reg = 0; reg < 4; ++reg) {
        int row = w * 16 + g * 4 + reg;
        sP[(row * 64 + ctl * 16 + r) ^ ((row & 7) << 3)] = f2bf(ps[ctl][reg]);
      }
    bf16x8 pf[2];
    #pragma unroll
    for (int kk = 0; kk < 2; ++kk) {
      int row = w * 16 + r;
      pf[kk] = *(const bf16x8*)(sP + ((row * 64 + kk * 32 + g * 8) ^ ((row & 7) << 3)));
    }
    #pragma unroll
    for (int nt = 0; nt < 4; ++nt)
      #pragma unroll
      for (int kk = 0; kk < 2; ++kk) {
        int vr = nt * 16 + r;
        bf16x8 vf = *(const bf16x8*)(sV + ((vr * 64 + kk * 32 + g * 8) ^ ((vr & 7) << 3)));
        o[nt] = __builtin_amdgcn_mfma_f32_16x16x32_bf16(pf[kk], vf, o[nt], 0, 0, 0);
      }
  }
  // write y [B,T,H*D] bf16
  #pragma unroll
  for (int nt = 0; nt < 4; ++nt)
    #pragma unroll
    for (int reg = 0; reg < 4; ++reg) {
      int t = q0 + w * 16 + g * 4 + reg;
      Y[((size_t)(b * T_ + t)) * C_ + h * 64 + nt * 16 + r] = f2bf(o[nt][reg] / l_run[reg]);
    }
}

extern "C" void kernel_launch(void* const* d_in, const int* in_sizes, int n_in,
                              void* d_out, int out_size, void* d_ws, size_t ws_size,
                              hipStream_t stream) {
  const float* x     = (const float*)d_in[0];
  const float* W_in  = (const float*)d_in[1];
  const float* b_in  = (const float*)d_in[2];
  const float* W_out = (const float*)d_in[3];
  const float* b_out = (const float*)d_in[4];
  float* out = (float*)d_out;

  const size_t NE = (size_t)B_ * H_ * T_ * D_;   // 8388608 per tensor
  u16* Qb    = (u16*)d_ws;
  u16* Kb    = Qb + NE;
  u16* Vb    = Kb + NE;
  u16* xbf   = Vb + NE;                           // reused as ybf after GEMM1
  u16* WtIn  = xbf + (size_t)M_ * C_;
  u16* WtOut = WtIn + (size_t)N3_ * C_;
  float* ctab = (float*)(WtOut + (size_t)C_ * C_);
  float* stab = ctab + T_ * 32;
  u16* ybf = xbf;

  size_t needed = (size_t)((char*)(stab + T_ * 32) - (char*)d_ws);
  if (ws_size < needed) return;  // workspace too small; fail visibly

  k_convert<<<4096, 256, 0, stream>>>(x, xbf, (M_ * C_) / 8);
  k_transpose<<<dim3(N3_ / 64, C_ / 64), 256, 0, stream>>>(W_in, WtIn, C_, N3_);
  k_transpose<<<dim3(C_ / 64, C_ / 64), 256, 0, stream>>>(W_out, WtOut, C_, C_);
  k_rope_table<<<(T_ * 32) / 256, 256, 0, stream>>>(ctab, stab);

  k_gemm<0><<<dim3(N3_ / 128, M_ / 128), 256, 0, stream>>>(
      xbf, WtIn, b_in, nullptr, Qb, Kb, Vb, M_, N3_, C_);

  k_rope<<<(int)(NE / 8 / 256), 256, 0, stream>>>(Qb, ctab, stab);
  k_rope<<<(int)(NE / 8 / 256), 256, 0, stream>>>(Kb, ctab, stab);

  k_attn<<<dim3(T_ / 64, H_, B_), 256, 0, stream>>>(Qb, Kb, Vb, ybf);

  k_gemm<1><<<dim3(C_ / 128, M_ / 128), 256, 0, stream>>>(
      ybf, WtOut, b_out, out, nullptr, nullptr, nullptr, M_, C_, C_);
}

// Round 2
// 296.271 us; speedup vs baseline: 1.6323x; 1.6323x over previous
//
#include <hip/hip_runtime.h>

#define B_ 4
#define T_ 2048
#define C_ 1024
#define H_ 16
#define D_ 64
#define M_ (B_*T_)    // 8192
#define N3_ (3*C_)    // 3072

typedef unsigned short u16;
typedef short bf16x8 __attribute__((ext_vector_type(8)));
typedef unsigned short u16x8 __attribute__((ext_vector_type(8)));
typedef unsigned short u16x4 __attribute__((ext_vector_type(4)));
typedef float f32x4 __attribute__((ext_vector_type(4)));

__device__ __forceinline__ u16 f2bf(float f) {
  unsigned u = __float_as_uint(f);
  u += 0x7fffu + ((u >> 16) & 1u);
  return (u16)(u >> 16);
}
__device__ __forceinline__ float bf2f(u16 u) { return __uint_as_float(((unsigned)u) << 16); }

__device__ __forceinline__ void gload16(const void* g, void* l) {
  __builtin_amdgcn_global_load_lds((const __attribute__((address_space(1))) void*)g,
                                   (__attribute__((address_space(3))) void*)l, 16, 0, 0);
}

// ---------------- elementwise f32 -> bf16 (vectorized, G13) ----------------
__global__ __launch_bounds__(256) void k_convert(const float* __restrict__ in,
                                                 u16* __restrict__ out, int n8) {
  int i = blockIdx.x * 256 + threadIdx.x;
  if (i >= n8) return;
  f32x4 a = *(const f32x4*)(in + (size_t)i * 8);
  f32x4 b = *(const f32x4*)(in + (size_t)i * 8 + 4);
  u16x8 o;
  #pragma unroll
  for (int j = 0; j < 4; ++j) { o[j] = f2bf(a[j]); o[4 + j] = f2bf(b[j]); }
  *(u16x8*)(out + (size_t)i * 8) = o;
}

// ---------------- transpose+convert: W [K][N] f32 -> Wt [N][K] bf16 ----------------
__global__ __launch_bounds__(256) void k_transpose(const float* __restrict__ W,
                                                   u16* __restrict__ Wt, int K, int N) {
  __shared__ float tile[64][65];
  int n0 = blockIdx.x * 64, k0 = blockIdx.y * 64;
  int c = threadIdx.x & 63, r0 = threadIdx.x >> 6;
  #pragma unroll
  for (int i = 0; i < 16; ++i) {
    int r = i * 4 + r0;
    tile[r][c] = W[(size_t)(k0 + r) * N + n0 + c];
  }
  __syncthreads();
  #pragma unroll
  for (int i = 0; i < 16; ++i) {
    int r = i * 4 + r0;
    Wt[(size_t)(n0 + r) * K + k0 + c] = f2bf(tile[c][r]);
  }
}

// ---------------- RoPE cos/sin tables (double precision on device) ----------------
__global__ void k_rope_table(float* __restrict__ ct, float* __restrict__ st) {
  int idx = blockIdx.x * 256 + threadIdx.x;   // T_*32 entries
  int t = idx >> 5, i = idx & 31;
  double inv = exp(-(2.0 * (double)i / 64.0) * log(10000.0));
  double a = (double)t * inv;
  ct[idx] = (float)cos(a);
  st[idx] = (float)sin(a);
}

// ---------------- RoPE in-place on [B,H,T,D] bf16 ----------------
__global__ __launch_bounds__(256) void k_rope(u16* __restrict__ X,
                                              const float* __restrict__ ct,
                                              const float* __restrict__ st) {
  int e = blockIdx.x * 256 + threadIdx.x;     // B*H*T*8 threads, 8 elems each
  int d0 = (e & 7) * 8;
  int t = (e >> 3) & (T_ - 1);
  size_t base = (size_t)e * 8;
  u16x8 v = *(const u16x8*)(X + base);
  f32x4 cv = *(const f32x4*)(ct + t * 32 + d0 / 2);
  f32x4 sv = *(const f32x4*)(st + t * 32 + d0 / 2);
  u16x8 o;
  #pragma unroll
  for (int p = 0; p < 4; ++p) {
    float x1 = bf2f(v[2 * p]), x2 = bf2f(v[2 * p + 1]);
    o[2 * p]     = f2bf(x1 * cv[p] - x2 * sv[p]);
    o[2 * p + 1] = f2bf(x2 * cv[p] + x1 * sv[p]);
  }
  *(u16x8*)(X + base) = o;
}

// ---------------- bf16 GEMM: A[M][K] @ Bt[N][K]^T + bias ----------------
// 128x128 tile, BK=64, 4 waves, global_load_lds w/ pre-swizzled source (T2).
// MODE 0: scatter to Q/K [B,H,T,D] and V [B,H,D,T] bf16.  MODE 1: fp32 C[M][N].
template <int MODE>
__global__ __launch_bounds__(256) void k_gemm(const u16* __restrict__ A,
                                              const u16* __restrict__ Bt,
                                              const float* __restrict__ bias,
                                              float* __restrict__ Cout,
                                              u16* __restrict__ Qb, u16* __restrict__ Kb,
                                              u16* __restrict__ Vt,
                                              int Md, int Nd, int Kd) {
  __shared__ u16 sA[128 * 64];
  __shared__ u16 sB[128 * 64];
  const int tid = threadIdx.x, lane = tid & 63, w = tid >> 6;
  const int g = lane >> 4, r = lane & 15;
  const int wm = w >> 1, wn = w & 1;
  const int tM = blockIdx.y * 128, tN = blockIdx.x * 128;

  f32x4 acc[4][4];
  #pragma unroll
  for (int i = 0; i < 4; ++i)
    #pragma unroll
    for (int j = 0; j < 4; ++j) acc[i][j] = (f32x4){0.f, 0.f, 0.f, 0.f};

  for (int k0 = 0; k0 < Kd; k0 += 64) {
    #pragma unroll
    for (int i = 0; i < 4; ++i) {
      int c = i * 256 + tid, row = c >> 3, slot = (c & 7) ^ (row & 7);
      gload16(A + (size_t)(tM + row) * Kd + k0 + slot * 8, sA + (i * 256 + w * 64) * 8);
    }
    #pragma unroll
    for (int i = 0; i < 4; ++i) {
      int c = i * 256 + tid, row = c >> 3, slot = (c & 7) ^ (row & 7);
      gload16(Bt + (size_t)(tN + row) * Kd + k0 + slot * 8, sB + (i * 256 + w * 64) * 8);
    }
    __syncthreads();
    bf16x8 af[4][2], bfr[4][2];
    #pragma unroll
    for (int mt = 0; mt < 4; ++mt)
      #pragma unroll
      for (int kk = 0; kk < 2; ++kk) {
        int row = wm * 64 + mt * 16 + r;
        af[mt][kk] = *(const bf16x8*)(sA + ((row * 64 + kk * 32 + g * 8) ^ ((row & 7) << 3)));
      }
    #pragma unroll
    for (int nt = 0; nt < 4; ++nt)
      #pragma unroll
      for (int kk = 0; kk < 2; ++kk) {
        int row = wn * 64 + nt * 16 + r;
        bfr[nt][kk] = *(const bf16x8*)(sB + ((row * 64 + kk * 32 + g * 8) ^ ((row & 7) << 3)));
      }
    #pragma unroll
    for (int mt = 0; mt < 4; ++mt)
      #pragma unroll
      for (int nt = 0; nt < 4; ++nt)
        #pragma unroll
        for (int kk = 0; kk < 2; ++kk)
          acc[mt][nt] = __builtin_amdgcn_mfma_f32_16x16x32_bf16(af[mt][kk], bfr[nt][kk],
                                                                acc[mt][nt], 0, 0, 0);
    __syncthreads();
  }

  // epilogue: C/D layout col = lane&15, row = (lane>>4)*4 + reg
  #pragma unroll
  for (int mt = 0; mt < 4; ++mt)
    #pragma unroll
    for (int nt = 0; nt < 4; ++nt) {
      int n = tN + wn * 64 + nt * 16 + r;
      float bv = bias[n];
      if (MODE == 1) {
        #pragma unroll
        for (int reg = 0; reg < 4; ++reg) {
          int m = tM + wm * 64 + mt * 16 + g * 4 + reg;
          Cout[(size_t)m * Nd + n] = acc[mt][nt][reg] + bv;
        }
      } else {
        int sec = n >> 10, idx = n & 1023, hh = idx >> 6, dd = idx & 63;
        #pragma unroll
        for (int reg = 0; reg < 4; ++reg) {
          int m = tM + wm * 64 + mt * 16 + g * 4 + reg;
          int bb = m >> 11, tt = m & (T_ - 1);
          u16 val = f2bf(acc[mt][nt][reg] + bv);
          if (sec == 0)
            Qb[((size_t)(bb * H_ + hh) * T_ + tt) * D_ + dd] = val;
          else if (sec == 1)
            Kb[((size_t)(bb * H_ + hh) * T_ + tt) * D_ + dd] = val;
          else
            Vt[((size_t)(bb * H_ + hh) * D_ + dd) * T_ + tt] = val;   // V pre-transposed
        }
      }
    }
}

// ---------------- causal flash attention, bf16 MFMA ----------------
// 64 q-rows/block (4 waves x 16). Swapped QK^T (S^T = K·Q^T) => per-lane
// key-row softmax; V pre-transposed [B,H,D,T] => staged like K (no in-loop
// transpose); double-buffered K/V staging, one barrier per KV tile.
__global__ __launch_bounds__(256) void k_attn(const u16* __restrict__ Qb,
                                              const u16* __restrict__ Kb,
                                              const u16* __restrict__ Vt,
                                              u16* __restrict__ Y) {
  __shared__ u16 sK[2][64 * 64];
  __shared__ u16 sV[2][64 * 64];
  __shared__ u16 sP[64 * 64];
  const int tid = threadIdx.x, lane = tid & 63, w = tid >> 6;
  const int g = lane >> 4, r = lane & 15;
  const int qt = (gridDim.x - 1) - blockIdx.x;      // longest blocks first
  const int h = blockIdx.y, b = blockIdx.z;
  const int q0 = qt * 64;
  const size_t bhK = ((size_t)b * H_ + h) * T_;     // K row base (keys)
  const size_t bhV = ((size_t)b * H_ + h) * D_;     // Vt row base (d)

  // Q fragment, pre-scaled by 1/sqrt(D)=0.125 (exact in bf16)
  bf16x8 qf[2];
  {
    int q = q0 + w * 16 + r;
    #pragma unroll
    for (int kk = 0; kk < 2; ++kk) {
      u16x8 v = *(const u16x8*)(Qb + (bhK + q) * D_ + kk * 32 + g * 8);
      u16x8 o;
      #pragma unroll
      for (int j = 0; j < 8; ++j) o[j] = f2bf(bf2f(v[j]) * 0.125f);
      qf[kk] = (bf16x8)o;
    }
  }

  float m_run = -1e30f, l_run = 0.f;
  f32x4 o[4];
  #pragma unroll
  for (int i = 0; i < 4; ++i) o[i] = (f32x4){0.f, 0.f, 0.f, 0.f};

  auto STAGE = [&](int buf, int kt) {
    #pragma unroll
    for (int i = 0; i < 2; ++i) {
      int c = i * 256 + tid, row = c >> 3, slot = (c & 7) ^ (row & 7);
      gload16(Kb + (bhK + kt * 64 + row) * D_ + slot * 8, &sK[buf][(i * 256 + w * 64) * 8]);
    }
    #pragma unroll
    for (int i = 0; i < 2; ++i) {
      int c = i * 256 + tid, row = c >> 3, slot = (c & 7) ^ (row & 7);
      gload16(Vt + (bhV + row) * T_ + kt * 64 + slot * 8, &sV[buf][(i * 256 + w * 64) * 8]);
    }
  };

  STAGE(0, 0);
  __syncthreads();

  const int prow = w * 16 + r;
  for (int kt = 0; kt <= qt; ++kt) {
    int cur = kt & 1;
    if (kt < qt) STAGE(cur ^ 1, kt + 1);      // prefetch next tile (overlaps compute)

    // S^T = K·Q^T  (lane: q = w*16+r fixed, keys ctl*16+g*4+reg)
    f32x4 s[4];
    #pragma unroll
    for (int ctl = 0; ctl < 4; ++ctl) {
      f32x4 a = (f32x4){0.f, 0.f, 0.f, 0.f};
      #pragma unroll
      for (int kk = 0; kk < 2; ++kk) {
        int row = ctl * 16 + r;
        bf16x8 kf = *(const bf16x8*)(&sK[cur][(row * 64 + kk * 32 + g * 8) ^ ((row & 7) << 3)]);
        a = __builtin_amdgcn_mfma_f32_16x16x32_bf16(kf, qf[kk], a, 0, 0, 0);
      }
      s[ctl] = a;
    }
    if (kt == qt) {  // diagonal: mask key > q (local indices, same tile)
      #pragma unroll
      for (int ctl = 0; ctl < 4; ++ctl)
        #pragma unroll
        for (int reg = 0; reg < 4; ++reg)
          if (ctl * 16 + g * 4 + reg > w * 16 + r) s[ctl][reg] = -1e30f;
    }

    // per-lane row max over 16 keys (tree), then combine 4 dup lanes
    float t0 = fmaxf(fmaxf(s[0][0], s[0][1]), fmaxf(s[0][2], s[0][3]));
    float t1 = fmaxf(fmaxf(s[1][0], s[1][1]), fmaxf(s[1][2], s[1][3]));
    float t2 = fmaxf(fmaxf(s[2][0], s[2][1]), fmaxf(s[2][2], s[2][3]));
    float t3 = fmaxf(fmaxf(s[3][0], s[3][1]), fmaxf(s[3][2], s[3][3]));
    float tm = fmaxf(fmaxf(t0, t1), fmaxf(t2, t3));
    tm = fmaxf(tm, __shfl_xor(tm, 16));
    tm = fmaxf(tm, __shfl_xor(tm, 32));

    float mn = fmaxf(m_run, tm);
    float f = __expf(m_run - mn);
    m_run = mn;

    float rs = 0.f;
    u16x4 pw[4];
    #pragma unroll
    for (int ctl = 0; ctl < 4; ++ctl) {
      #pragma unroll
      for (int reg = 0; reg < 4; ++reg) {
        float p = __expf(s[ctl][reg] - mn);
        rs += p;
        pw[ctl][reg] = f2bf(p);
      }
    }
    rs += __shfl_xor(rs, 16);
    rs += __shfl_xor(rs, 32);
    l_run = l_run * f + rs;

    // P^T -> sP rows=q (4 consecutive keys per lane -> b64 writes)
    #pragma unroll
    for (int ctl = 0; ctl < 4; ++ctl)
      *(u16x4*)(&sP[(prow * 64 + ctl * 16 + g * 4) ^ ((prow & 7) << 3)]) = pw[ctl];

    // rescale O by per-row factor (broadcast f from lane q&15)
    float fb[4];
    #pragma unroll
    for (int reg = 0; reg < 4; ++reg) fb[reg] = __shfl(f, g * 4 + reg);
    #pragma unroll
    for (int nt = 0; nt < 4; ++nt)
      #pragma unroll
      for (int reg = 0; reg < 4; ++reg) o[nt][reg] *= fb[reg];

    // PV: O += P·V  (A = P rows q, B = V^T rows d)
    bf16x8 pf[2];
    #pragma unroll
    for (int kk = 0; kk < 2; ++kk)
      pf[kk] = *(const bf16x8*)(&sP[(prow * 64 + kk * 32 + g * 8) ^ ((prow & 7) << 3)]);
    #pragma unroll
    for (int nt = 0; nt < 4; ++nt) {
      #pragma unroll
      for (int kk = 0; kk < 2; ++kk) {
        int vr = nt * 16 + r;
        bf16x8 vf = *(const bf16x8*)(&sV[cur][(vr * 64 + kk * 32 + g * 8) ^ ((vr & 7) << 3)]);
        o[nt] = __builtin_amdgcn_mfma_f32_16x16x32_bf16(pf[kk], vf, o[nt], 0, 0, 0);
      }
    }
    __syncthreads();   // next-tile loads landed; current buffers free to overwrite
  }

  // write y [B,T,H*D] bf16 (broadcast l from lane q&15)
  float lb[4];
  #pragma unroll
  for (int reg = 0; reg < 4; ++reg) lb[reg] = __shfl(l_run, g * 4 + reg);
  #pragma unroll
  for (int nt = 0; nt < 4; ++nt)
    #pragma unroll
    for (int reg = 0; reg < 4; ++reg) {
      int t = q0 + w * 16 + g * 4 + reg;
      Y[((size_t)(b * T_ + t)) * C_ + h * 64 + nt * 16 + r] = f2bf(o[nt][reg] / lb[reg]);
    }
}

extern "C" void kernel_launch(void* const* d_in, const int* in_sizes, int n_in,
                              void* d_out, int out_size, void* d_ws, size_t ws_size,
                              hipStream_t stream) {
  const float* x     = (const float*)d_in[0];
  const float* W_in  = (const float*)d_in[1];
  const float* b_in  = (const float*)d_in[2];
  const float* W_out = (const float*)d_in[3];
  const float* b_out = (const float*)d_in[4];
  float* out = (float*)d_out;

  const size_t NE = (size_t)B_ * H_ * T_ * D_;   // 8388608 per tensor
  u16* Qb    = (u16*)d_ws;
  u16* Kb    = Qb + NE;
  u16* Vt    = Kb + NE;                           // [B,H,D,T]
  u16* xbf   = Vt + NE;                           // reused as ybf after attn
  u16* WtIn  = xbf + (size_t)M_ * C_;
  u16* WtOut = WtIn + (size_t)N3_ * C_;
  float* ctab = (float*)(WtOut + (size_t)C_ * C_);
  float* stab = ctab + T_ * 32;
  u16* ybf = xbf;

  size_t needed = (size_t)((char*)(stab + T_ * 32) - (char*)d_ws);
  if (ws_size < needed) return;  // workspace too small; fail visibly

  k_convert<<<4096, 256, 0, stream>>>(x, xbf, (M_ * C_) / 8);
  k_transpose<<<dim3(N3_ / 64, C_ / 64), 256, 0, stream>>>(W_in, WtIn, C_, N3_);
  k_transpose<<<dim3(C_ / 64, C_ / 64), 256, 0, stream>>>(W_out, WtOut, C_, C_);
  k_rope_table<<<(T_ * 32) / 256, 256, 0, stream>>>(ctab, stab);

  k_gemm<0><<<dim3(N3_ / 128, M_ / 128), 256, 0, stream>>>(
      xbf, WtIn, b_in, nullptr, Qb, Kb, Vt, M_, N3_, C_);

  k_rope<<<(int)(NE / 8 / 256), 256, 0, stream>>>(Qb, ctab, stab);
  k_rope<<<(int)(NE / 8 / 256), 256, 0, stream>>>(Kb, ctab, stab);

  k_attn<<<dim3(T_ / 64, H_, B_), 256, 0, stream>>>(Qb, Kb, Vt, ybf);

  k_gemm<1><<<dim3(C_ / 128, M_ / 128), 256, 0, stream>>>(
      ybf, WtOut, b_out, out, nullptr, nullptr, nullptr, M_, C_, C_);
}

// Round 3
// 286.989 us; speedup vs baseline: 1.6851x; 1.0323x over previous
//
#include <hip/hip_runtime.h>

#define B_ 4
#define T_ 2048
#define C_ 1024
#define H_ 16
#define D_ 64
#define M_ (B_*T_)    // 8192
#define N3_ (3*C_)    // 3072

typedef unsigned short u16;
typedef short bf16x8 __attribute__((ext_vector_type(8)));
typedef unsigned short u16x8 __attribute__((ext_vector_type(8)));
typedef unsigned int u32x2 __attribute__((ext_vector_type(2)));
typedef float f32x4 __attribute__((ext_vector_type(4)));

#define QSCALE 0.18033688f   /* 0.125 * log2(e): softmax done in exp2 domain */
#define DEFER_THR 11.0f      /* defer-max threshold in log2 units (~8 nats) */

__device__ __forceinline__ u16 f2bf(float f) {
  unsigned u = __float_as_uint(f);
  u += 0x7fffu + ((u >> 16) & 1u);
  return (u16)(u >> 16);
}
__device__ __forceinline__ float bf2f(u16 u) { return __uint_as_float(((unsigned)u) << 16); }

__device__ __forceinline__ unsigned cvt_pk_bf16(float lo, float hi) {
  unsigned r;
  asm("v_cvt_pk_bf16_f32 %0, %1, %2" : "=v"(r) : "v"(lo), "v"(hi));
  return r;
}

__device__ __forceinline__ void gload16(const void* g, void* l) {
  __builtin_amdgcn_global_load_lds((const __attribute__((address_space(1))) void*)g,
                                   (__attribute__((address_space(3))) void*)l, 16, 0, 0);
}

// ---------------- elementwise f32 -> bf16 ----------------
__global__ __launch_bounds__(256) void k_convert(const float* __restrict__ in,
                                                 u16* __restrict__ out, int n8) {
  int i = blockIdx.x * 256 + threadIdx.x;
  if (i >= n8) return;
  f32x4 a = *(const f32x4*)(in + (size_t)i * 8);
  f32x4 b = *(const f32x4*)(in + (size_t)i * 8 + 4);
  u16x8 o;
  #pragma unroll
  for (int j = 0; j < 4; ++j) { o[j] = f2bf(a[j]); o[4 + j] = f2bf(b[j]); }
  *(u16x8*)(out + (size_t)i * 8) = o;
}

// ---------------- transpose+convert: W [K][N] f32 -> Wt [N][K] bf16 ----------------
__global__ __launch_bounds__(256) void k_transpose(const float* __restrict__ W,
                                                   u16* __restrict__ Wt, int K, int N) {
  __shared__ float tile[64][65];
  int n0 = blockIdx.x * 64, k0 = blockIdx.y * 64;
  int c = threadIdx.x & 63, r0 = threadIdx.x >> 6;
  #pragma unroll
  for (int i = 0; i < 16; ++i) {
    int r = i * 4 + r0;
    tile[r][c] = W[(size_t)(k0 + r) * N + n0 + c];
  }
  __syncthreads();
  #pragma unroll
  for (int i = 0; i < 16; ++i) {
    int r = i * 4 + r0;
    Wt[(size_t)(n0 + r) * K + k0 + c] = f2bf(tile[c][r]);
  }
}

// ---------------- RoPE cos/sin tables (double precision on device) ----------------
__global__ void k_rope_table(float* __restrict__ ct, float* __restrict__ st) {
  int idx = blockIdx.x * 256 + threadIdx.x;   // T_*32 entries
  int t = idx >> 5, i = idx & 31;
  double inv = exp(-(2.0 * (double)i / 64.0) * log(10000.0));
  double a = (double)t * inv;
  ct[idx] = (float)cos(a);
  st[idx] = (float)sin(a);
}

// ---------------- V [B,H,T,D] bf16 -> Vt [B,H,D,T] bf16 ----------------
__global__ __launch_bounds__(256) void k_vtrans(const u16* __restrict__ V,
                                                u16* __restrict__ Vt) {
  __shared__ u16 tile[64][65];
  int t0 = blockIdx.x * 64;
  size_t bh = (size_t)blockIdx.z * H_ + blockIdx.y;
  const u16* src = V + (bh * T_ + t0) * D_;
  u16* dst = Vt + bh * (size_t)D_ * T_ + t0;
  int r0 = threadIdx.x >> 3, c0 = (threadIdx.x & 7) * 8;
  #pragma unroll
  for (int i = 0; i < 2; ++i) {
    int rr = i * 32 + r0;
    u16x8 v = *(const u16x8*)(src + rr * D_ + c0);
    #pragma unroll
    for (int j = 0; j < 8; ++j) tile[rr][c0 + j] = v[j];
  }
  __syncthreads();
  #pragma unroll
  for (int i = 0; i < 2; ++i) {
    int d = i * 32 + r0;
    u16x8 o;
    #pragma unroll
    for (int j = 0; j < 8; ++j) o[j] = tile[c0 + j][d];
    *(u16x8*)(dst + (size_t)d * T_ + c0) = o;
  }
}

// ---------------- bf16 GEMM: A[M][K] @ Bt[N][K]^T + bias ----------------
// MODE 0: fused RoPE (Q pre-scaled by QSCALE), scatter Q/K/V [B,H,T,D] bf16.
// MODE 1: fp32 C[M][N].
template <int MODE>
__global__ __launch_bounds__(256) void k_gemm(const u16* __restrict__ A,
                                              const u16* __restrict__ Bt,
                                              const float* __restrict__ bias,
                                              float* __restrict__ Cout,
                                              u16* __restrict__ Qb, u16* __restrict__ Kb,
                                              u16* __restrict__ Vb,
                                              const float* __restrict__ ctab,
                                              const float* __restrict__ stab,
                                              int Md, int Nd, int Kd) {
  __shared__ u16 sA[128 * 64];
  __shared__ u16 sB[128 * 64];
  const int tid = threadIdx.x, lane = tid & 63, w = tid >> 6;
  const int g = lane >> 4, r = lane & 15;
  const int wm = w >> 1, wn = w & 1;
  const int tM = blockIdx.y * 128, tN = blockIdx.x * 128;

  f32x4 acc[4][4];
  #pragma unroll
  for (int i = 0; i < 4; ++i)
    #pragma unroll
    for (int j = 0; j < 4; ++j) acc[i][j] = (f32x4){0.f, 0.f, 0.f, 0.f};

  for (int k0 = 0; k0 < Kd; k0 += 64) {
    #pragma unroll
    for (int i = 0; i < 4; ++i) {
      int c = i * 256 + tid, row = c >> 3, slot = (c & 7) ^ (row & 7);
      gload16(A + (size_t)(tM + row) * Kd + k0 + slot * 8, sA + (i * 256 + w * 64) * 8);
    }
    #pragma unroll
    for (int i = 0; i < 4; ++i) {
      int c = i * 256 + tid, row = c >> 3, slot = (c & 7) ^ (row & 7);
      gload16(Bt + (size_t)(tN + row) * Kd + k0 + slot * 8, sB + (i * 256 + w * 64) * 8);
    }
    __syncthreads();
    bf16x8 af[4][2], bfr[4][2];
    #pragma unroll
    for (int mt = 0; mt < 4; ++mt)
      #pragma unroll
      for (int kk = 0; kk < 2; ++kk) {
        int row = wm * 64 + mt * 16 + r;
        af[mt][kk] = *(const bf16x8*)(sA + ((row * 64 + kk * 32 + g * 8) ^ ((row & 7) << 3)));
      }
    #pragma unroll
    for (int nt = 0; nt < 4; ++nt)
      #pragma unroll
      for (int kk = 0; kk < 2; ++kk) {
        int row = wn * 64 + nt * 16 + r;
        bfr[nt][kk] = *(const bf16x8*)(sB + ((row * 64 + kk * 32 + g * 8) ^ ((row & 7) << 3)));
      }
    __builtin_amdgcn_s_setprio(1);
    #pragma unroll
    for (int mt = 0; mt < 4; ++mt)
      #pragma unroll
      for (int nt = 0; nt < 4; ++nt)
        #pragma unroll
        for (int kk = 0; kk < 2; ++kk)
          acc[mt][nt] = __builtin_amdgcn_mfma_f32_16x16x32_bf16(af[mt][kk], bfr[nt][kk],
                                                                acc[mt][nt], 0, 0, 0);
    __builtin_amdgcn_s_setprio(0);
    __syncthreads();
  }

  // epilogue: C/D layout col = lane&15, row = (lane>>4)*4 + reg
  #pragma unroll
  for (int mt = 0; mt < 4; ++mt)
    #pragma unroll
    for (int nt = 0; nt < 4; ++nt) {
      int n = tN + wn * 64 + nt * 16 + r;
      float bv = bias[n];
      if (MODE == 1) {
        #pragma unroll
        for (int reg = 0; reg < 4; ++reg) {
          int m = tM + wm * 64 + mt * 16 + g * 4 + reg;
          Cout[(size_t)m * Nd + n] = acc[mt][nt][reg] + bv;
        }
      } else {
        int sec = n >> 10, idx = n & 1023, hh = idx >> 6, dd = idx & 63;
        #pragma unroll
        for (int reg = 0; reg < 4; ++reg) {
          int m = tM + wm * 64 + mt * 16 + g * 4 + reg;
          int bb = m >> 11, tt = m & (T_ - 1);
          float v = acc[mt][nt][reg] + bv;
          if (sec < 2) {   // fused RoPE on Q,K (pairs = adjacent lanes, DPP shfl)
            float pv = __shfl_xor(v, 1);
            int pi = tt * 32 + (dd >> 1);
            float c = ctab[pi], sn = stab[pi];
            v = (dd & 1) ? (v * c + pv * sn) : (v * c - pv * sn);
            if (sec == 0) v *= QSCALE;   // fold softmax scale into Q (commutes w/ rotation)
          }
          u16 val = f2bf(v);
          size_t off = ((size_t)(bb * H_ + hh) * T_ + tt) * D_ + dd;
          if (sec == 0) Qb[off];
          if (sec == 0) Qb[off] = val;
          else if (sec == 1) Kb[off] = val;
          else Vb[off] = val;   // row-major; transposed by k_vtrans afterwards
        }
      }
    }
}

// ---------------- causal flash attention, bf16 MFMA ----------------
// 64 q-rows/block (4 waves x 16). Swapped QK^T; exp2-domain softmax with
// defer-max (per-lane partial l, cross-lane combine once at end); V
// pre-transposed [B,H,D,T]; double-buffered staging, 1 barrier/tile.
__global__ __launch_bounds__(256) void k_attn(const u16* __restrict__ Qb,
                                              const u16* __restrict__ Kb,
                                              const u16* __restrict__ Vt,
                                              u16* __restrict__ Y) {
  __shared__ u16 sK[2][64 * 64];
  __shared__ u16 sV[2][64 * 64];
  __shared__ u16 sP[64 * 64];
  const int tid = threadIdx.x, lane = tid & 63, w = tid >> 6;
  const int g = lane >> 4, r = lane & 15;
  const int qt = (gridDim.x - 1) - blockIdx.x;      // longest blocks first
  const int h = blockIdx.y, b = blockIdx.z;
  const int q0 = qt * 64;
  const size_t bhK = ((size_t)b * H_ + h) * T_;
  const size_t bhV = ((size_t)b * H_ + h) * D_;

  bf16x8 qf[2];
  {
    int q = q0 + w * 16 + r;
    qf[0] = *(const bf16x8*)(Qb + (bhK + q) * D_ + g * 8);
    qf[1] = *(const bf16x8*)(Qb + (bhK + q) * D_ + 32 + g * 8);
  }

  float m_run = -3e38f, l_run = 0.f;    // per-lane partial l (combined at end)
  f32x4 o[4];
  #pragma unroll
  for (int i = 0; i < 4; ++i) o[i] = (f32x4){0.f, 0.f, 0.f, 0.f};

  auto STAGE = [&](int buf, int kt) {
    #pragma unroll
    for (int i = 0; i < 2; ++i) {
      int c = i * 256 + tid, row = c >> 3, slot = (c & 7) ^ (row & 7);
      gload16(Kb + (bhK + kt * 64 + row) * D_ + slot * 8, &sK[buf][(i * 256 + w * 64) * 8]);
    }
    #pragma unroll
    for (int i = 0; i < 2; ++i) {
      int c = i * 256 + tid, row = c >> 3, slot = (c & 7) ^ (row & 7);
      gload16(Vt + (bhV + row) * T_ + kt * 64 + slot * 8, &sV[buf][(i * 256 + w * 64) * 8]);
    }
  };

  STAGE(0, 0);
  __syncthreads();

  const int prow = w * 16 + r;
  for (int kt = 0; kt <= qt; ++kt) {
    int cur = kt & 1;
    if (kt < qt) STAGE(cur ^ 1, kt + 1);      // prefetch next tile

    // S^T = K·Q^T (log2 domain; Q pre-scaled). lane: q = w*16+r, keys ctl*16+g*4+reg
    f32x4 s[4];
    __builtin_amdgcn_s_setprio(1);
    #pragma unroll
    for (int ctl = 0; ctl < 4; ++ctl) {
      f32x4 a = (f32x4){0.f, 0.f, 0.f, 0.f};
      #pragma unroll
      for (int kk = 0; kk < 2; ++kk) {
        int row = ctl * 16 + r;
        bf16x8 kf = *(const bf16x8*)(&sK[cur][(row * 64 + kk * 32 + g * 8) ^ ((row & 7) << 3)]);
        a = __builtin_amdgcn_mfma_f32_16x16x32_bf16(kf, qf[kk], a, 0, 0, 0);
      }
      s[ctl] = a;
    }
    __builtin_amdgcn_s_setprio(0);
    if (kt == qt) {
      #pragma unroll
      for (int ctl = 0; ctl < 4; ++ctl)
        #pragma unroll
        for (int reg = 0; reg < 4; ++reg)
          if (ctl * 16 + g * 4 + reg > w * 16 + r) s[ctl][reg] = -3e38f;
    }

    // per-lane max over this lane's 16 keys
    float pm = fmaxf(fmaxf(fmaxf(s[0][0], s[0][1]), fmaxf(s[0][2], s[0][3])),
                     fmaxf(fmaxf(s[1][0], s[1][1]), fmaxf(s[1][2], s[1][3])));
    pm = fmaxf(pm, fmaxf(fmaxf(fmaxf(s[2][0], s[2][1]), fmaxf(s[2][2], s[2][3])),
                         fmaxf(fmaxf(s[3][0], s[3][1]), fmaxf(s[3][2], s[3][3]))));

    if (__any(pm > m_run + DEFER_THR)) {      // rare: true max + rescale
      float tm = pm;
      tm = fmaxf(tm, __shfl_xor(tm, 16));
      tm = fmaxf(tm, __shfl_xor(tm, 32));
      float mn = fmaxf(m_run, tm);
      float f = exp2f(m_run - mn);
      m_run = mn;
      float fb[4];
      #pragma unroll
      for (int reg = 0; reg < 4; ++reg) fb[reg] = __shfl(f, g * 4 + reg);
      #pragma unroll
      for (int nt = 0; nt < 4; ++nt)
        #pragma unroll
        for (int reg = 0; reg < 4; ++reg) o[nt][reg] *= fb[reg];
      l_run *= f;
    }

    // P = exp2(S - m); accumulate per-lane partial denominator
    float p[4][4];
    float rs = 0.f;
    #pragma unroll
    for (int ctl = 0; ctl < 4; ++ctl)
      #pragma unroll
      for (int reg = 0; reg < 4; ++reg) {
        float pp = exp2f(s[ctl][reg] - m_run);
        p[ctl][reg] = pp;
        rs += pp;
      }
    l_run += rs;

    // P -> sP (packed cvt_pk, b64 writes; rows = own wave's band, no barrier)
    #pragma unroll
    for (int ctl = 0; ctl < 4; ++ctl) {
      u32x2 w2;
      w2[0] = cvt_pk_bf16(p[ctl][0], p[ctl][1]);
      w2[1] = cvt_pk_bf16(p[ctl][2], p[ctl][3]);
      *(u32x2*)(&sP[(prow * 64 + ctl * 16 + g * 4) ^ ((prow & 7) << 3)]) = w2;
    }

    // PV: O += P·V
    bf16x8 pf[2];
    #pragma unroll
    for (int kk = 0; kk < 2; ++kk)
      pf[kk] = *(const bf16x8*)(&sP[(prow * 64 + kk * 32 + g * 8) ^ ((prow & 7) << 3)]);
    __builtin_amdgcn_s_setprio(1);
    #pragma unroll
    for (int nt = 0; nt < 4; ++nt) {
      #pragma unroll
      for (int kk = 0; kk < 2; ++kk) {
        int vr = nt * 16 + r;
        bf16x8 vf = *(const bf16x8*)(&sV[cur][(vr * 64 + kk * 32 + g * 8) ^ ((vr & 7) << 3)]);
        o[nt] = __builtin_amdgcn_mfma_f32_16x16x32_bf16(pf[kk], vf, o[nt], 0, 0, 0);
      }
    }
    __builtin_amdgcn_s_setprio(0);
    __syncthreads();
  }

  // combine per-lane partial l across the 4 duplicate lanes, then write y
  l_run += __shfl_xor(l_run, 16);
  l_run += __shfl_xor(l_run, 32);
  float lb[4];
  #pragma unroll
  for (int reg = 0; reg < 4; ++reg) lb[reg] = __shfl(l_run, g * 4 + reg);
  #pragma unroll
  for (int nt = 0; nt < 4; ++nt)
    #pragma unroll
    for (int reg = 0; reg < 4; ++reg) {
      int t = q0 + w * 16 + g * 4 + reg;
      Y[((size_t)(b * T_ + t)) * C_ + h * 64 + nt * 16 + r] = f2bf(o[nt][reg] / lb[reg]);
    }
}

extern "C" void kernel_launch(void* const* d_in, const int* in_sizes, int n_in,
                              void* d_out, int out_size, void* d_ws, size_t ws_size,
                              hipStream_t stream) {
  const float* x     = (const float*)d_in[0];
  const float* W_in  = (const float*)d_in[1];
  const float* b_in  = (const float*)d_in[2];
  const float* W_out = (const float*)d_in[3];
  const float* b_out = (const float*)d_in[4];
  float* out = (float*)d_out;

  const size_t NE = (size_t)B_ * H_ * T_ * D_;   // 8388608
  u16* Qb    = (u16*)d_ws;
  u16* Kb    = Qb + NE;
  u16* Vb    = Kb + NE;     // row-major V from GEMM1; becomes ybf after vtrans
  u16* xbf   = Vb + NE;     // GEMM1 A-input; becomes Vt after GEMM1
  u16* WtIn  = xbf + (size_t)M_ * C_;
  u16* WtOut = WtIn + (size_t)N3_ * C_;
  float* ctab = (float*)(WtOut + (size_t)C_ * C_);
  float* stab = ctab + T_ * 32;
  u16* Vt  = xbf;   // overlays xbf (dead after GEMM1)
  u16* ybf = Vb;    // overlays Vb  (dead after k_vtrans)

  size_t needed = (size_t)((char*)(stab + T_ * 32) - (char*)d_ws);
  if (ws_size < needed) return;

  k_convert<<<4096, 256, 0, stream>>>(x, xbf, (M_ * C_) / 8);
  k_transpose<<<dim3(N3_ / 64, C_ / 64), 256, 0, stream>>>(W_in, WtIn, C_, N3_);
  k_transpose<<<dim3(C_ / 64, C_ / 64), 256, 0, stream>>>(W_out, WtOut, C_, C_);
  k_rope_table<<<(T_ * 32) / 256, 256, 0, stream>>>(ctab, stab);

  k_gemm<0><<<dim3(N3_ / 128, M_ / 128), 256, 0, stream>>>(
      xbf, WtIn, b_in, nullptr, Qb, Kb, Vb, ctab, stab, M_, N3_, C_);

  k_vtrans<<<dim3(T_ / 64, H_, B_), 256, 0, stream>>>(Vb, Vt);

  k_attn<<<dim3(T_ / 64, H_, B_), 256, 0, stream>>>(Qb, Kb, Vt, ybf);

  k_gemm<1><<<dim3(C_ / 128, M_ / 128), 256, 0, stream>>>(
      ybf, WtOut, b_out, out, nullptr, nullptr, nullptr, nullptr, nullptr, M_, C_, C_);
}

// Round 4
// 266.743 us; speedup vs baseline: 1.8130x; 1.0759x over previous
//
#include <hip/hip_runtime.h>

#define B_ 4
#define T_ 2048
#define C_ 1024
#define H_ 16
#define D_ 64
#define M_ (B_*T_)    // 8192
#define N3_ (3*C_)    // 3072

typedef unsigned short u16;
typedef short bf16x8 __attribute__((ext_vector_type(8)));
typedef short bf16x4 __attribute__((ext_vector_type(4)));
typedef unsigned short u16x8 __attribute__((ext_vector_type(8)));
typedef unsigned int u32x4 __attribute__((ext_vector_type(4)));
typedef float f32x4 __attribute__((ext_vector_type(4)));
typedef float f32x16 __attribute__((ext_vector_type(16)));

#define QSCALE 0.18033688f   /* 0.125 * log2(e): softmax done in exp2 domain */
#define DEFER_THR 11.0f      /* defer-max threshold in log2 units (~8 nats) */

__device__ __forceinline__ u16 f2bf(float f) {
  unsigned u = __float_as_uint(f);
  u += 0x7fffu + ((u >> 16) & 1u);
  return (u16)(u >> 16);
}
__device__ __forceinline__ float bf2f(u16 u) { return __uint_as_float(((unsigned)u) << 16); }

__device__ __forceinline__ unsigned cvt_pk_bf16(float lo, float hi) {
  unsigned r;
  asm("v_cvt_pk_bf16_f32 %0, %1, %2" : "=v"(r) : "v"(lo), "v"(hi));
  return r;
}

__device__ __forceinline__ void gload16(const void* g, void* l) {
  __builtin_amdgcn_global_load_lds((const __attribute__((address_space(1))) void*)g,
                                   (__attribute__((address_space(3))) void*)l, 16, 0, 0);
}

// ---------------- elementwise f32 -> bf16 ----------------
__global__ __launch_bounds__(256) void k_convert(const float* __restrict__ in,
                                                 u16* __restrict__ out, int n8) {
  int i = blockIdx.x * 256 + threadIdx.x;
  if (i >= n8) return;
  f32x4 a = *(const f32x4*)(in + (size_t)i * 8);
  f32x4 b = *(const f32x4*)(in + (size_t)i * 8 + 4);
  u16x8 o;
  #pragma unroll
  for (int j = 0; j < 4; ++j) { o[j] = f2bf(a[j]); o[4 + j] = f2bf(b[j]); }
  *(u16x8*)(out + (size_t)i * 8) = o;
}

// ---------------- transpose+convert: W [K][N] f32 -> Wt [N][K] bf16 ----------------
__global__ __launch_bounds__(256) void k_transpose(const float* __restrict__ W,
                                                   u16* __restrict__ Wt, int K, int N) {
  __shared__ float tile[64][65];
  int n0 = blockIdx.x * 64, k0 = blockIdx.y * 64;
  int c = threadIdx.x & 63, r0 = threadIdx.x >> 6;
  #pragma unroll
  for (int i = 0; i < 16; ++i) {
    int r = i * 4 + r0;
    tile[r][c] = W[(size_t)(k0 + r) * N + n0 + c];
  }
  __syncthreads();
  #pragma unroll
  for (int i = 0; i < 16; ++i) {
    int r = i * 4 + r0;
    Wt[(size_t)(n0 + r) * K + k0 + c] = f2bf(tile[c][r]);
  }
}

// ---------------- RoPE cos/sin tables (double precision on device) ----------------
__global__ void k_rope_table(float* __restrict__ ct, float* __restrict__ st) {
  int idx = blockIdx.x * 256 + threadIdx.x;   // T_*32 entries
  int t = idx >> 5, i = idx & 31;
  double inv = exp(-(2.0 * (double)i / 64.0) * log(10000.0));
  double a = (double)t * inv;
  ct[idx] = (float)cos(a);
  st[idx] = (float)sin(a);
}

// ---------------- V [B,H,T,D] bf16 -> Vt [B,H,D,T] bf16 ----------------
__global__ __launch_bounds__(256) void k_vtrans(const u16* __restrict__ V,
                                                u16* __restrict__ Vt) {
  __shared__ u16 tile[64][65];
  int t0 = blockIdx.x * 64;
  size_t bh = (size_t)blockIdx.z * H_ + blockIdx.y;
  const u16* src = V + (bh * T_ + t0) * D_;
  u16* dst = Vt + bh * (size_t)D_ * T_ + t0;
  int r0 = threadIdx.x >> 3, c0 = (threadIdx.x & 7) * 8;
  #pragma unroll
  for (int i = 0; i < 2; ++i) {
    int rr = i * 32 + r0;
    u16x8 v = *(const u16x8*)(src + rr * D_ + c0);
    #pragma unroll
    for (int j = 0; j < 8; ++j) tile[rr][c0 + j] = v[j];
  }
  __syncthreads();
  #pragma unroll
  for (int i = 0; i < 2; ++i) {
    int d = i * 32 + r0;
    u16x8 o;
    #pragma unroll
    for (int j = 0; j < 8; ++j) o[j] = tile[c0 + j][d];
    *(u16x8*)(dst + (size_t)d * T_ + c0) = o;
  }
}

// ---------------- bf16 GEMM: A[M][K] @ Bt[N][K]^T + bias ----------------
// MODE 0: fused RoPE (Q pre-scaled by QSCALE), scatter Q/K/V [B,H,T,D] bf16.
// MODE 1: fp32 C[M][N].  XCD-aware block swizzle (grid size % 8 == 0).
template <int MODE>
__global__ __launch_bounds__(256) void k_gemm(const u16* __restrict__ A,
                                              const u16* __restrict__ Bt,
                                              const float* __restrict__ bias,
                                              float* __restrict__ Cout,
                                              u16* __restrict__ Qb, u16* __restrict__ Kb,
                                              u16* __restrict__ Vb,
                                              const float* __restrict__ ctab,
                                              const float* __restrict__ stab,
                                              int Md, int Nd, int Kd) {
  __shared__ u16 sA[128 * 64];
  __shared__ u16 sB[128 * 64];
  const int tid = threadIdx.x, lane = tid & 63, w = tid >> 6;
  const int g = lane >> 4, r = lane & 15;
  const int wm = w >> 1, wn = w & 1;
  // XCD swizzle: contiguous chunk of blocks per XCD
  const int gx = gridDim.x;
  const int lin = blockIdx.y * gx + blockIdx.x;
  const int cpx = (gx * gridDim.y) >> 3;
  const int swz = (lin & 7) * cpx + (lin >> 3);
  const int tM = (swz / gx) * 128, tN = (swz % gx) * 128;

  f32x4 acc[4][4];
  #pragma unroll
  for (int i = 0; i < 4; ++i)
    #pragma unroll
    for (int j = 0; j < 4; ++j) acc[i][j] = (f32x4){0.f, 0.f, 0.f, 0.f};

  for (int k0 = 0; k0 < Kd; k0 += 64) {
    #pragma unroll
    for (int i = 0; i < 4; ++i) {
      int c = i * 256 + tid, row = c >> 3, slot = (c & 7) ^ (row & 7);
      gload16(A + (size_t)(tM + row) * Kd + k0 + slot * 8, sA + (i * 256 + w * 64) * 8);
    }
    #pragma unroll
    for (int i = 0; i < 4; ++i) {
      int c = i * 256 + tid, row = c >> 3, slot = (c & 7) ^ (row & 7);
      gload16(Bt + (size_t)(tN + row) * Kd + k0 + slot * 8, sB + (i * 256 + w * 64) * 8);
    }
    __syncthreads();
    bf16x8 af[4][2], bfr[4][2];
    #pragma unroll
    for (int mt = 0; mt < 4; ++mt)
      #pragma unroll
      for (int kk = 0; kk < 2; ++kk) {
        int row = wm * 64 + mt * 16 + r;
        af[mt][kk] = *(const bf16x8*)(sA + ((row * 64 + kk * 32 + g * 8) ^ ((row & 7) << 3)));
      }
    #pragma unroll
    for (int nt = 0; nt < 4; ++nt)
      #pragma unroll
      for (int kk = 0; kk < 2; ++kk) {
        int row = wn * 64 + nt * 16 + r;
        bfr[nt][kk] = *(const bf16x8*)(sB + ((row * 64 + kk * 32 + g * 8) ^ ((row & 7) << 3)));
      }
    __builtin_amdgcn_s_setprio(1);
    #pragma unroll
    for (int mt = 0; mt < 4; ++mt)
      #pragma unroll
      for (int nt = 0; nt < 4; ++nt)
        #pragma unroll
        for (int kk = 0; kk < 2; ++kk)
          acc[mt][nt] = __builtin_amdgcn_mfma_f32_16x16x32_bf16(af[mt][kk], bfr[nt][kk],
                                                                acc[mt][nt], 0, 0, 0);
    __builtin_amdgcn_s_setprio(0);
    __syncthreads();
  }

  // epilogue: C/D layout col = lane&15, row = (lane>>4)*4 + reg
  #pragma unroll
  for (int mt = 0; mt < 4; ++mt)
    #pragma unroll
    for (int nt = 0; nt < 4; ++nt) {
      int n = tN + wn * 64 + nt * 16 + r;
      float bv = bias[n];
      if (MODE == 1) {
        #pragma unroll
        for (int reg = 0; reg < 4; ++reg) {
          int m = tM + wm * 64 + mt * 16 + g * 4 + reg;
          Cout[(size_t)m * Nd + n] = acc[mt][nt][reg] + bv;
        }
      } else {
        int sec = n >> 10, idx = n & 1023, hh = idx >> 6, dd = idx & 63;
        #pragma unroll
        for (int reg = 0; reg < 4; ++reg) {
          int m = tM + wm * 64 + mt * 16 + g * 4 + reg;
          int bb = m >> 11, tt = m & (T_ - 1);
          float v = acc[mt][nt][reg] + bv;
          if (sec < 2) {   // fused RoPE on Q,K (pairs = adjacent lanes, DPP shfl)
            float pv = __shfl_xor(v, 1);
            int pi = tt * 32 + (dd >> 1);
            float c = ctab[pi], sn = stab[pi];
            v = (dd & 1) ? (v * c + pv * sn) : (v * c - pv * sn);
            if (sec == 0) v *= QSCALE;   // fold softmax scale into Q
          }
          u16 val = f2bf(v);
          size_t off = ((size_t)(bb * H_ + hh) * T_ + tt) * D_ + dd;
          if (sec == 0) Qb[off] = val;
          else if (sec == 1) Kb[off] = val;
          else Vb[off] = val;   // row-major; transposed by k_vtrans afterwards
        }
      }
    }
}

// ---------------- causal flash attention, 32x32 MFMA ----------------
// 4 waves x 32 q-rows = 128 q/block, KV tiles of 64. Swapped QK^T
// (S^T = K·Q^T, col=q=lane&31) AND swapped PV (O^T = V^T·P^T) so each
// lane owns one q end-to-end: P never leaves registers (the MFMA k-dim
// permutation of P packs is mirrored in the Vt LDS read offsets).
// exp2-domain softmax, defer-max; double-buffered K/V staging.
__global__ __launch_bounds__(256) void k_attn(const u16* __restrict__ Qb,
                                              const u16* __restrict__ Kb,
                                              const u16* __restrict__ Vt,
                                              u16* __restrict__ Y) {
  __shared__ u16 sK[2][64 * 64];
  __shared__ u16 sV[2][64 * 64];
  const int tid = threadIdx.x, w = tid >> 6;
  const int lane = tid & 63, col = lane & 31, hi = lane >> 5;
  const int qtb = (gridDim.x - 1) - blockIdx.x;      // longest blocks first
  const int h = blockIdx.y, b = blockIdx.z;
  const int q0 = qtb * 128;
  const int qw = q0 + w * 32;          // wave's q range: [qw, qw+32)
  const int tq = qw + col;             // this lane's q-row
  const size_t bhK = ((size_t)b * H_ + h) * T_;
  const size_t bhV = ((size_t)b * H_ + h) * D_;

  // Q fragments (B-operand): qf[c] = Q[tq][c*16 + hi*8 .. +8]  (Q pre-scaled)
  bf16x8 qf[4];
  #pragma unroll
  for (int c = 0; c < 4; ++c)
    qf[c] = *(const bf16x8*)(Qb + (bhK + tq) * D_ + c * 16 + hi * 8);

  float m_run = -3e38f, l_run = 0.f;
  f32x16 o0, o1;                       // O^T: col=q (own), rows d (16 regs x 2 tiles)
  #pragma unroll
  for (int i = 0; i < 16; ++i) { o0[i] = 0.f; o1[i] = 0.f; }

  auto STAGE = [&](int buf, int kt) {
    #pragma unroll
    for (int i = 0; i < 2; ++i) {
      int c = i * 256 + tid, row = c >> 3, slot = (c & 7) ^ (row & 7);
      gload16(Kb + (bhK + kt * 64 + row) * D_ + slot * 8, &sK[buf][(i * 256 + w * 64) * 8]);
    }
    #pragma unroll
    for (int i = 0; i < 2; ++i) {
      int c = i * 256 + tid, row = c >> 3, slot = (c & 7) ^ (row & 7);
      gload16(Vt + (bhV + row) * T_ + kt * 64 + slot * 8, &sV[buf][(i * 256 + w * 64) * 8]);
    }
  };

  STAGE(0, 0);
  __syncthreads();

  const int ntiles = 2 * qtb + 2;
  for (int kt = 0; kt < ntiles; ++kt) {
    const int cur = kt & 1;
    if (kt + 1 < ntiles) STAGE(cur ^ 1, kt + 1);   // prefetch next tile
    const int kb = kt * 64;
    if (kb <= qw + 31) {                           // wave has live keys here
      const bool act1 = (kb + 32 <= qw + 31);      // subtile 1 live?
      f32x16 s0, s1;
      #pragma unroll
      for (int i = 0; i < 16; ++i) { s0[i] = 0.f; s1[i] = 0.f; }

      // S^T = K·Q^T  (A rows = keys, B cols = q)
      __builtin_amdgcn_s_setprio(1);
      #pragma unroll
      for (int c = 0; c < 4; ++c) {
        int row = col;
        bf16x8 kf = *(const bf16x8*)(&sK[cur][(row * 64 + c * 16 + hi * 8) ^ ((row & 7) << 3)]);
        s0 = __builtin_amdgcn_mfma_f32_32x32x16_bf16(kf, qf[c], s0, 0, 0, 0);
      }
      if (act1) {
        #pragma unroll
        for (int c = 0; c < 4; ++c) {
          int row = 32 + col;
          bf16x8 kf = *(const bf16x8*)(&sK[cur][(row * 64 + c * 16 + hi * 8) ^ ((row & 7) << 3)]);
          s1 = __builtin_amdgcn_mfma_f32_32x32x16_bf16(kf, qf[c], s1, 0, 0, 0);
        }
      }
      __builtin_amdgcn_s_setprio(0);

      // causal mask: key(reg) = kb + st*32 + (reg&3) + 8*(reg>>2) + 4*hi
      if (kb + 31 > qw) {
        #pragma unroll
        for (int reg = 0; reg < 16; ++reg) {
          int key = kb + (reg & 3) + 8 * (reg >> 2) + 4 * hi;
          if (key > tq) s0[reg] = -3e38f;
        }
      }
      if (act1 && kb + 63 > qw) {
        #pragma unroll
        for (int reg = 0; reg < 16; ++reg) {
          int key = kb + 32 + (reg & 3) + 8 * (reg >> 2) + 4 * hi;
          if (key > tq) s1[reg] = -3e38f;
        }
      }

      // per-lane max (defer-max: cross-lane only when max grows > THR)
      float pm = s0[0];
      #pragma unroll
      for (int reg = 1; reg < 16; ++reg) pm = fmaxf(pm, s0[reg]);
      if (act1) {
        #pragma unroll
        for (int reg = 0; reg < 16; ++reg) pm = fmaxf(pm, s1[reg]);
      }
      if (__any(pm > m_run + DEFER_THR)) {
        float tm = fmaxf(pm, __shfl_xor(pm, 32));   // pair (lane, lane+32) = same q
        float mn = fmaxf(m_run, tm);
        float f = __builtin_amdgcn_exp2f(m_run - mn);
        m_run = mn;
        #pragma unroll
        for (int i = 0; i < 16; ++i) { o0[i] *= f; o1[i] *= f; }
        l_run *= f;
      }

      // P = exp2(S - m) in place; per-lane partial denominator
      #pragma unroll
      for (int reg = 0; reg < 16; ++reg) {
        s0[reg] = __builtin_amdgcn_exp2f(s0[reg] - m_run);
        l_run += s0[reg];
      }
      if (act1) {
        #pragma unroll
        for (int reg = 0; reg < 16; ++reg) {
          s1[reg] = __builtin_amdgcn_exp2f(s1[reg] - m_run);
          l_run += s1[reg];
        }
      }

      // PV: O^T += V^T·P^T.  B-frag = own P packs (keys 16u+4hi+{0..3,8..11});
      // A-frag reads Vt at the SAME permuted key offsets.
      __builtin_amdgcn_s_setprio(1);
      #pragma unroll
      for (int st = 0; st < 2; ++st) {
        if (st == 1 && !act1) break;
        #pragma unroll
        for (int u = 0; u < 2; ++u) {
          u32x4 pw;
          #pragma unroll
          for (int j = 0; j < 4; ++j) {
            int jr = (4 * u + j) * 2;
            pw[j] = st ? cvt_pk_bf16(s1[jr], s1[jr + 1])
                       : cvt_pk_bf16(s0[jr], s0[jr + 1]);
          }
          bf16x8 pf = __builtin_bit_cast(bf16x8, pw);
          const int keybase = st * 32 + u * 16;
          #pragma unroll
          for (int dt = 0; dt < 2; ++dt) {
            int row = dt * 32 + col;
            int e0 = (row * 64 + keybase + 4 * hi) ^ ((row & 7) << 3);
            int e1 = (row * 64 + keybase + 8 + 4 * hi) ^ ((row & 7) << 3);
            bf16x4 vlo = *(const bf16x4*)(&sV[cur][e0]);
            bf16x4 vhi = *(const bf16x4*)(&sV[cur][e1]);
            bf16x8 vf;
            vf[0] = vlo[0]; vf[1] = vlo[1]; vf[2] = vlo[2]; vf[3] = vlo[3];
            vf[4] = vhi[0]; vf[5] = vhi[1]; vf[6] = vhi[2]; vf[7] = vhi[3];
            if (dt == 0) o0 = __builtin_amdgcn_mfma_f32_32x32x16_bf16(vf, pf, o0, 0, 0, 0);
            else         o1 = __builtin_amdgcn_mfma_f32_32x32x16_bf16(vf, pf, o1, 0, 0, 0);
          }
        }
      }
      __builtin_amdgcn_s_setprio(0);
    }
    __syncthreads();   // next-tile staging landed; buffers swap
  }

  // finalize: combine pair-partial l, divide, store O^T (d from reg formula)
  l_run += __shfl_xor(l_run, 32);
  float rl = 1.0f / l_run;
  u16* yrow = Y + ((size_t)b * T_ + tq) * C_ + h * 64;
  #pragma unroll
  for (int dt = 0; dt < 2; ++dt)
    #pragma unroll
    for (int j = 0; j < 8; ++j) {
      float a0 = (dt ? o1[2 * j] : o0[2 * j]) * rl;
      float a1 = (dt ? o1[2 * j + 1] : o0[2 * j + 1]) * rl;
      int d = dt * 32 + 8 * (j >> 1) + 4 * hi + 2 * (j & 1);
      *(unsigned*)(yrow + d) = cvt_pk_bf16(a0, a1);
    }
}

extern "C" void kernel_launch(void* const* d_in, const int* in_sizes, int n_in,
                              void* d_out, int out_size, void* d_ws, size_t ws_size,
                              hipStream_t stream) {
  const float* x     = (const float*)d_in[0];
  const float* W_in  = (const float*)d_in[1];
  const float* b_in  = (const float*)d_in[2];
  const float* W_out = (const float*)d_in[3];
  const float* b_out = (const float*)d_in[4];
  float* out = (float*)d_out;

  const size_t NE = (size_t)B_ * H_ * T_ * D_;   // 8388608
  u16* Qb    = (u16*)d_ws;
  u16* Kb    = Qb + NE;
  u16* Vb    = Kb + NE;     // row-major V from GEMM1; becomes ybf after vtrans
  u16* xbf   = Vb + NE;     // GEMM1 A-input; becomes Vt after GEMM1
  u16* WtIn  = xbf + (size_t)M_ * C_;
  u16* WtOut = WtIn + (size_t)N3_ * C_;
  float* ctab = (float*)(WtOut + (size_t)C_ * C_);
  float* stab = ctab + T_ * 32;
  u16* Vt  = xbf;   // overlays xbf (dead after GEMM1)
  u16* ybf = Vb;    // overlays Vb  (dead after k_vtrans)

  size_t needed = (size_t)((char*)(stab + T_ * 32) - (char*)d_ws);
  if (ws_size < needed) return;

  k_convert<<<4096, 256, 0, stream>>>(x, xbf, (M_ * C_) / 8);
  k_transpose<<<dim3(N3_ / 64, C_ / 64), 256, 0, stream>>>(W_in, WtIn, C_, N3_);
  k_transpose<<<dim3(C_ / 64, C_ / 64), 256, 0, stream>>>(W_out, WtOut, C_, C_);
  k_rope_table<<<(T_ * 32) / 256, 256, 0, stream>>>(ctab, stab);

  k_gemm<0><<<dim3(N3_ / 128, M_ / 128), 256, 0, stream>>>(
      xbf, WtIn, b_in, nullptr, Qb, Kb, Vb, ctab, stab, M_, N3_, C_);

  k_vtrans<<<dim3(T_ / 64, H_, B_), 256, 0, stream>>>(Vb, Vt);

  k_attn<<<dim3(T_ / 128, H_, B_), 256, 0, stream>>>(Qb, Kb, Vt, ybf);

  k_gemm<1><<<dim3(C_ / 128, M_ / 128), 256, 0, stream>>>(
      ybf, WtOut, b_out, out, nullptr, nullptr, nullptr, nullptr, nullptr, M_, C_, C_);
}

// Round 5
// 224.570 us; speedup vs baseline: 2.1535x; 1.1878x over previous
//
#include <hip/hip_runtime.h>

#define B_ 4
#define T_ 2048
#define C_ 1024
#define H_ 16
#define D_ 64
#define M_ (B_*T_)    // 8192
#define N3_ (3*C_)    // 3072
#define NKT_ 32       // number of 64-row q-tiles (= T/64)

typedef unsigned short u16;
typedef short bf16x8 __attribute__((ext_vector_type(8)));
typedef short bf16x4 __attribute__((ext_vector_type(4)));
typedef unsigned short u16x8 __attribute__((ext_vector_type(8)));
typedef unsigned int u32x4 __attribute__((ext_vector_type(4)));
typedef float f32x4 __attribute__((ext_vector_type(4)));
typedef float f32x16 __attribute__((ext_vector_type(16)));

#define QSCALE 0.18033688f   /* 0.125 * log2(e): softmax done in exp2 domain */
#define DEFER_THR 11.0f      /* defer-max threshold in log2 units (~8 nats) */

__device__ __forceinline__ u16 f2bf(float f) {
  unsigned u = __float_as_uint(f);
  u += 0x7fffu + ((u >> 16) & 1u);
  return (u16)(u >> 16);
}
__device__ __forceinline__ float bf2f(u16 u) { return __uint_as_float(((unsigned)u) << 16); }

__device__ __forceinline__ unsigned cvt_pk_bf16(float lo, float hi) {
  unsigned r;
  asm("v_cvt_pk_bf16_f32 %0, %1, %2" : "=v"(r) : "v"(lo), "v"(hi));
  return r;
}

__device__ __forceinline__ void gload16(const void* g, void* l) {
  __builtin_amdgcn_global_load_lds((const __attribute__((address_space(1))) void*)g,
                                   (__attribute__((address_space(3))) void*)l, 16, 0, 0);
}

// ---------------- elementwise f32 -> bf16 ----------------
__global__ __launch_bounds__(256) void k_convert(const float* __restrict__ in,
                                                 u16* __restrict__ out, int n8) {
  int i = blockIdx.x * 256 + threadIdx.x;
  if (i >= n8) return;
  f32x4 a = *(const f32x4*)(in + (size_t)i * 8);
  f32x4 b = *(const f32x4*)(in + (size_t)i * 8 + 4);
  u16x8 o;
  #pragma unroll
  for (int j = 0; j < 4; ++j) { o[j] = f2bf(a[j]); o[4 + j] = f2bf(b[j]); }
  *(u16x8*)(out + (size_t)i * 8) = o;
}

// ---------------- transpose+convert: W [K][N] f32 -> Wt [N][K] bf16 ----------------
__global__ __launch_bounds__(256) void k_transpose(const float* __restrict__ W,
                                                   u16* __restrict__ Wt, int K, int N) {
  __shared__ float tile[64][65];
  int n0 = blockIdx.x * 64, k0 = blockIdx.y * 64;
  int c = threadIdx.x & 63, r0 = threadIdx.x >> 6;
  #pragma unroll
  for (int i = 0; i < 16; ++i) {
    int r = i * 4 + r0;
    tile[r][c] = W[(size_t)(k0 + r) * N + n0 + c];
  }
  __syncthreads();
  #pragma unroll
  for (int i = 0; i < 16; ++i) {
    int r = i * 4 + r0;
    Wt[(size_t)(n0 + r) * K + k0 + c] = f2bf(tile[c][r]);
  }
}

// ---------------- RoPE cos/sin tables (double precision on device) ----------------
__global__ void k_rope_table(float* __restrict__ ct, float* __restrict__ st) {
  int idx = blockIdx.x * 256 + threadIdx.x;   // T_*32 entries
  int t = idx >> 5, i = idx & 31;
  double inv = exp(-(2.0 * (double)i / 64.0) * log(10000.0));
  double a = (double)t * inv;
  ct[idx] = (float)cos(a);
  st[idx] = (float)sin(a);
}

// ---------------- V [B,H,T,D] bf16 -> Vt [B,H,D,T] bf16 ----------------
__global__ __launch_bounds__(256) void k_vtrans(const u16* __restrict__ V,
                                                u16* __restrict__ Vt) {
  __shared__ u16 tile[64][65];
  int t0 = blockIdx.x * 64;
  size_t bh = (size_t)blockIdx.z * H_ + blockIdx.y;
  const u16* src = V + (bh * T_ + t0) * D_;
  u16* dst = Vt + bh * (size_t)D_ * T_ + t0;
  int r0 = threadIdx.x >> 3, c0 = (threadIdx.x & 7) * 8;
  #pragma unroll
  for (int i = 0; i < 2; ++i) {
    int rr = i * 32 + r0;
    u16x8 v = *(const u16x8*)(src + rr * D_ + c0);
    #pragma unroll
    for (int j = 0; j < 8; ++j) tile[rr][c0 + j] = v[j];
  }
  __syncthreads();
  #pragma unroll
  for (int i = 0; i < 2; ++i) {
    int d = i * 32 + r0;
    u16x8 o;
    #pragma unroll
    for (int j = 0; j < 8; ++j) o[j] = tile[c0 + j][d];
    *(u16x8*)(dst + (size_t)d * T_ + c0) = o;
  }
}

// ---------------- bf16 GEMM: A[M][K] @ Bt[N][K]^T + bias ----------------
// MODE 0: fused RoPE (Q pre-scaled by QSCALE), scatter Q/K/V [B,H,T,D] bf16.
// MODE 1: fp32 C[M][N].  XCD-aware block swizzle (grid size % 8 == 0).
template <int MODE>
__global__ __launch_bounds__(256) void k_gemm(const u16* __restrict__ A,
                                              const u16* __restrict__ Bt,
                                              const float* __restrict__ bias,
                                              float* __restrict__ Cout,
                                              u16* __restrict__ Qb, u16* __restrict__ Kb,
                                              u16* __restrict__ Vb,
                                              const float* __restrict__ ctab,
                                              const float* __restrict__ stab,
                                              int Md, int Nd, int Kd) {
  __shared__ u16 sA[128 * 64];
  __shared__ u16 sB[128 * 64];
  const int tid = threadIdx.x, lane = tid & 63, w = tid >> 6;
  const int g = lane >> 4, r = lane & 15;
  const int wm = w >> 1, wn = w & 1;
  // XCD swizzle: contiguous chunk of blocks per XCD
  const int gx = gridDim.x;
  const int lin = blockIdx.y * gx + blockIdx.x;
  const int cpx = (gx * gridDim.y) >> 3;
  const int swz = (lin & 7) * cpx + (lin >> 3);
  const int tM = (swz / gx) * 128, tN = (swz % gx) * 128;

  f32x4 acc[4][4];
  #pragma unroll
  for (int i = 0; i < 4; ++i)
    #pragma unroll
    for (int j = 0; j < 4; ++j) acc[i][j] = (f32x4){0.f, 0.f, 0.f, 0.f};

  for (int k0 = 0; k0 < Kd; k0 += 64) {
    #pragma unroll
    for (int i = 0; i < 4; ++i) {
      int c = i * 256 + tid, row = c >> 3, slot = (c & 7) ^ (row & 7);
      gload16(A + (size_t)(tM + row) * Kd + k0 + slot * 8, sA + (i * 256 + w * 64) * 8);
    }
    #pragma unroll
    for (int i = 0; i < 4; ++i) {
      int c = i * 256 + tid, row = c >> 3, slot = (c & 7) ^ (row & 7);
      gload16(Bt + (size_t)(tN + row) * Kd + k0 + slot * 8, sB + (i * 256 + w * 64) * 8);
    }
    __syncthreads();
    bf16x8 af[4][2], bfr[4][2];
    #pragma unroll
    for (int mt = 0; mt < 4; ++mt)
      #pragma unroll
      for (int kk = 0; kk < 2; ++kk) {
        int row = wm * 64 + mt * 16 + r;
        af[mt][kk] = *(const bf16x8*)(sA + ((row * 64 + kk * 32 + g * 8) ^ ((row & 7) << 3)));
      }
    #pragma unroll
    for (int nt = 0; nt < 4; ++nt)
      #pragma unroll
      for (int kk = 0; kk < 2; ++kk) {
        int row = wn * 64 + nt * 16 + r;
        bfr[nt][kk] = *(const bf16x8*)(sB + ((row * 64 + kk * 32 + g * 8) ^ ((row & 7) << 3)));
      }
    __builtin_amdgcn_s_setprio(1);
    #pragma unroll
    for (int mt = 0; mt < 4; ++mt)
      #pragma unroll
      for (int nt = 0; nt < 4; ++nt)
        #pragma unroll
        for (int kk = 0; kk < 2; ++kk)
          acc[mt][nt] = __builtin_amdgcn_mfma_f32_16x16x32_bf16(af[mt][kk], bfr[nt][kk],
                                                                acc[mt][nt], 0, 0, 0);
    __builtin_amdgcn_s_setprio(0);
    __syncthreads();
  }

  // epilogue: C/D layout col = lane&15, row = (lane>>4)*4 + reg
  #pragma unroll
  for (int mt = 0; mt < 4; ++mt)
    #pragma unroll
    for (int nt = 0; nt < 4; ++nt) {
      int n = tN + wn * 64 + nt * 16 + r;
      float bv = bias[n];
      if (MODE == 1) {
        #pragma unroll
        for (int reg = 0; reg < 4; ++reg) {
          int m = tM + wm * 64 + mt * 16 + g * 4 + reg;
          Cout[(size_t)m * Nd + n] = acc[mt][nt][reg] + bv;
        }
      } else {
        int sec = n >> 10, idx = n & 1023, hh = idx >> 6, dd = idx & 63;
        #pragma unroll
        for (int reg = 0; reg < 4; ++reg) {
          int m = tM + wm * 64 + mt * 16 + g * 4 + reg;
          int bb = m >> 11, tt = m & (T_ - 1);
          float v = acc[mt][nt][reg] + bv;
          if (sec < 2) {   // fused RoPE on Q,K (pairs = adjacent lanes, DPP shfl)
            float pv = __shfl_xor(v, 1);
            int pi = tt * 32 + (dd >> 1);
            float c = ctab[pi], sn = stab[pi];
            v = (dd & 1) ? (v * c + pv * sn) : (v * c - pv * sn);
            if (sec == 0) v *= QSCALE;   // fold softmax scale into Q
          }
          u16 val = f2bf(v);
          size_t off = ((size_t)(bb * H_ + hh) * T_ + tt) * D_ + dd;
          if (sec == 0) Qb[off] = val;
          else if (sec == 1) Kb[off] = val;
          else Vb[off] = val;   // row-major; transposed by k_vtrans afterwards
        }
      }
    }
}

// ---------------- causal flash attention, 32x32 MFMA, causal-paired ----------------
// Each block = 2 waves x 32 q = 64 q-rows, and processes TWO q-tiles:
// {pair, NKT-1-pair}. Work per block = (a+1)+(NKT-a) = NKT+1 KV-iters for
// every pair -> zero static imbalance (round-4 counters showed ~50% idle
// from same-qt-per-CU dispatch). Swapped QK^T and swapped PV (O^T = V^T.P^T):
// each lane owns one q end-to-end, P stays in registers. exp2-domain softmax
// with defer-max; double-buffered staging; cross-half prefetch (no bubble).
__global__ __launch_bounds__(128) void k_attn(const u16* __restrict__ Qb,
                                              const u16* __restrict__ Kb,
                                              const u16* __restrict__ Vt,
                                              u16* __restrict__ Y) {
  __shared__ u16 sK[2][64 * 64];
  __shared__ u16 sV[2][64 * 64];
  const int tid = threadIdx.x, w = tid >> 6;          // 2 waves
  const int lane = tid & 63, col = lane & 31, hi = lane >> 5;
  const int pair = blockIdx.x;                        // 0..NKT/2-1
  const int h = blockIdx.y, b = blockIdx.z;
  const size_t bhK = ((size_t)b * H_ + h) * T_;
  const size_t bhV = ((size_t)b * H_ + h) * D_;

  const int qtA = pair, qtB = (NKT_ - 1) - pair;
  const int ntA = qtA + 1;                            // KV tiles for half A
  const int total = NKT_ + 1;                         // ntA + (qtB+1)

  auto STAGE = [&](int buf, int kt) {
    #pragma unroll
    for (int i = 0; i < 4; ++i) {
      int c = i * 128 + tid, row = c >> 3, slot = (c & 7) ^ (row & 7);
      gload16(Kb + (bhK + kt * 64 + row) * D_ + slot * 8, &sK[buf][(i * 128 + w * 64) * 8]);
    }
    #pragma unroll
    for (int i = 0; i < 4; ++i) {
      int c = i * 128 + tid, row = c >> 3, slot = (c & 7) ^ (row & 7);
      gload16(Vt + (bhV + row) * T_ + kt * 64 + slot * 8, &sV[buf][(i * 128 + w * 64) * 8]);
    }
  };

  int qw = qtA * 64 + w * 32;          // wave's q range: [qw, qw+32)
  int tq = qw + col;                   // this lane's q-row
  bf16x8 qf[4];
  #pragma unroll
  for (int c = 0; c < 4; ++c)
    qf[c] = *(const bf16x8*)(Qb + (bhK + tq) * D_ + c * 16 + hi * 8);

  float m_run = -3e38f, l_run = 0.f;
  f32x16 o0, o1;                       // O^T: col=q (own), rows d
  #pragma unroll
  for (int i = 0; i < 16; ++i) { o0[i] = 0.f; o1[i] = 0.f; }

  auto FINAL = [&]() {
    float lr = l_run + __shfl_xor(l_run, 32);
    float rl = 1.0f / lr;
    u16* yrow = Y + ((size_t)b * T_ + tq) * C_ + h * 64;
    #pragma unroll
    for (int dt = 0; dt < 2; ++dt)
      #pragma unroll
      for (int j = 0; j < 8; ++j) {
        float a0 = (dt ? o1[2 * j] : o0[2 * j]) * rl;
        float a1 = (dt ? o1[2 * j + 1] : o0[2 * j + 1]) * rl;
        int d = dt * 32 + 8 * (j >> 1) + 4 * hi + 2 * (j & 1);
        *(unsigned*)(yrow + d) = cvt_pk_bf16(a0, a1);
      }
  };

  STAGE(0, 0);
  __syncthreads();

  for (int it = 0; it < total; ++it) {
    const int cur = it & 1;
    if (it + 1 < total) {               // prefetch next tile (maybe next half's kt=0)
      int nit = it + 1;
      STAGE(cur ^ 1, nit < ntA ? nit : nit - ntA);
    }
    const int ktl = it < ntA ? it : it - ntA;
    const int kb = ktl * 64;
    if (kb <= qw + 31) {                           // wave has live keys here
      const bool act1 = (kb + 32 <= qw + 31);      // subtile 1 live?
      f32x16 s0, s1;
      #pragma unroll
      for (int i = 0; i < 16; ++i) { s0[i] = 0.f; s1[i] = 0.f; }

      // S^T = K·Q^T  (A rows = keys, B cols = q)
      __builtin_amdgcn_s_setprio(1);
      #pragma unroll
      for (int c = 0; c < 4; ++c) {
        int row = col;
        bf16x8 kf = *(const bf16x8*)(&sK[cur][(row * 64 + c * 16 + hi * 8) ^ ((row & 7) << 3)]);
        s0 = __builtin_amdgcn_mfma_f32_32x32x16_bf16(kf, qf[c], s0, 0, 0, 0);
      }
      if (act1) {
        #pragma unroll
        for (int c = 0; c < 4; ++c) {
          int row = 32 + col;
          bf16x8 kf = *(const bf16x8*)(&sK[cur][(row * 64 + c * 16 + hi * 8) ^ ((row & 7) << 3)]);
          s1 = __builtin_amdgcn_mfma_f32_32x32x16_bf16(kf, qf[c], s1, 0, 0, 0);
        }
      }
      __builtin_amdgcn_s_setprio(0);

      // causal mask: key(reg) = kb + st*32 + (reg&3) + 8*(reg>>2) + 4*hi
      if (kb + 31 > qw) {
        #pragma unroll
        for (int reg = 0; reg < 16; ++reg) {
          int key = kb + (reg & 3) + 8 * (reg >> 2) + 4 * hi;
          if (key > tq) s0[reg] = -3e38f;
        }
      }
      if (act1 && kb + 63 > qw) {
        #pragma unroll
        for (int reg = 0; reg < 16; ++reg) {
          int key = kb + 32 + (reg & 3) + 8 * (reg >> 2) + 4 * hi;
          if (key > tq) s1[reg] = -3e38f;
        }
      }

      // per-lane max (defer-max: cross-lane only when max grows > THR)
      float pm = s0[0];
      #pragma unroll
      for (int reg = 1; reg < 16; ++reg) pm = fmaxf(pm, s0[reg]);
      if (act1) {
        #pragma unroll
        for (int reg = 0; reg < 16; ++reg) pm = fmaxf(pm, s1[reg]);
      }
      if (__any(pm > m_run + DEFER_THR)) {
        float tm = fmaxf(pm, __shfl_xor(pm, 32));   // pair (lane, lane+32) = same q
        float mn = fmaxf(m_run, tm);
        float f = __builtin_amdgcn_exp2f(m_run - mn);
        m_run = mn;
        #pragma unroll
        for (int i = 0; i < 16; ++i) { o0[i] *= f; o1[i] *= f; }
        l_run *= f;
      }

      // P = exp2(S - m) in place; per-lane partial denominator
      #pragma unroll
      for (int reg = 0; reg < 16; ++reg) {
        s0[reg] = __builtin_amdgcn_exp2f(s0[reg] - m_run);
        l_run += s0[reg];
      }
      if (act1) {
        #pragma unroll
        for (int reg = 0; reg < 16; ++reg) {
          s1[reg] = __builtin_amdgcn_exp2f(s1[reg] - m_run);
          l_run += s1[reg];
        }
      }

      // PV: O^T += V^T·P^T.  B-frag = own P packs (keys 16u+4hi+{0..3,8..11});
      // A-frag reads Vt at the SAME permuted key offsets.
      __builtin_amdgcn_s_setprio(1);
      #pragma unroll
      for (int st = 0; st < 2; ++st) {
        if (st == 1 && !act1) break;
        #pragma unroll
        for (int u = 0; u < 2; ++u) {
          u32x4 pw;
          #pragma unroll
          for (int j = 0; j < 4; ++j) {
            int jr = (4 * u + j) * 2;
            pw[j] = st ? cvt_pk_bf16(s1[jr], s1[jr + 1])
                       : cvt_pk_bf16(s0[jr], s0[jr + 1]);
          }
          bf16x8 pf = __builtin_bit_cast(bf16x8, pw);
          const int keybase = st * 32 + u * 16;
          #pragma unroll
          for (int dt = 0; dt < 2; ++dt) {
            int row = dt * 32 + col;
            int e0 = (row * 64 + keybase + 4 * hi) ^ ((row & 7) << 3);
            int e1 = (row * 64 + keybase + 8 + 4 * hi) ^ ((row & 7) << 3);
            bf16x4 vlo = *(const bf16x4*)(&sV[cur][e0]);
            bf16x4 vhi = *(const bf16x4*)(&sV[cur][e1]);
            bf16x8 vf;
            vf[0] = vlo[0]; vf[1] = vlo[1]; vf[2] = vlo[2]; vf[3] = vlo[3];
            vf[4] = vhi[0]; vf[5] = vhi[1]; vf[6] = vhi[2]; vf[7] = vhi[3];
            if (dt == 0) o0 = __builtin_amdgcn_mfma_f32_32x32x16_bf16(vf, pf, o0, 0, 0, 0);
            else         o1 = __builtin_amdgcn_mfma_f32_32x32x16_bf16(vf, pf, o1, 0, 0, 0);
          }
        }
      }
      __builtin_amdgcn_s_setprio(0);
    }
    __syncthreads();   // next-tile staging landed; buffers swap

    if (it == ntA - 1) {
      // finalize half A, reset state, switch to q-tile B (tile 0 already staged)
      FINAL();
      qw = qtB * 64 + w * 32;
      tq = qw + col;
      #pragma unroll
      for (int c = 0; c < 4; ++c)
        qf[c] = *(const bf16x8*)(Qb + (bhK + tq) * D_ + c * 16 + hi * 8);
      m_run = -3e38f; l_run = 0.f;
      #pragma unroll
      for (int i = 0; i < 16; ++i) { o0[i] = 0.f; o1[i] = 0.f; }
    }
  }
  FINAL();   // half B
}

extern "C" void kernel_launch(void* const* d_in, const int* in_sizes, int n_in,
                              void* d_out, int out_size, void* d_ws, size_t ws_size,
                              hipStream_t stream) {
  const float* x     = (const float*)d_in[0];
  const float* W_in  = (const float*)d_in[1];
  const float* b_in  = (const float*)d_in[2];
  const float* W_out = (const float*)d_in[3];
  const float* b_out = (const float*)d_in[4];
  float* out = (float*)d_out;

  const size_t NE = (size_t)B_ * H_ * T_ * D_;   // 8388608
  u16* Qb    = (u16*)d_ws;
  u16* Kb    = Qb + NE;
  u16* Vb    = Kb + NE;     // row-major V from GEMM1; becomes ybf after vtrans
  u16* xbf   = Vb + NE;     // GEMM1 A-input; becomes Vt after GEMM1
  u16* WtIn  = xbf + (size_t)M_ * C_;
  u16* WtOut = WtIn + (size_t)N3_ * C_;
  float* ctab = (float*)(WtOut + (size_t)C_ * C_);
  float* stab = ctab + T_ * 32;
  u16* Vt  = xbf;   // overlays xbf (dead after GEMM1)
  u16* ybf = Vb;    // overlays Vb  (dead after k_vtrans)

  size_t needed = (size_t)((char*)(stab + T_ * 32) - (char*)d_ws);
  if (ws_size < needed) return;

  k_convert<<<4096, 256, 0, stream>>>(x, xbf, (M_ * C_) / 8);
  k_transpose<<<dim3(N3_ / 64, C_ / 64), 256, 0, stream>>>(W_in, WtIn, C_, N3_);
  k_transpose<<<dim3(C_ / 64, C_ / 64), 256, 0, stream>>>(W_out, WtOut, C_, C_);
  k_rope_table<<<(T_ * 32) / 256, 256, 0, stream>>>(ctab, stab);

  k_gemm<0><<<dim3(N3_ / 128, M_ / 128), 256, 0, stream>>>(
      xbf, WtIn, b_in, nullptr, Qb, Kb, Vb, ctab, stab, M_, N3_, C_);

  k_vtrans<<<dim3(T_ / 64, H_, B_), 256, 0, stream>>>(Vb, Vt);

  k_attn<<<dim3(NKT_ / 2, H_, B_), 128, 0, stream>>>(Qb, Kb, Vt, ybf);

  k_gemm<1><<<dim3(C_ / 128, M_ / 128), 256, 0, stream>>>(
      ybf, WtOut, b_out, out, nullptr, nullptr, nullptr, nullptr, nullptr, M_, C_, C_);
}